// Round 4
// baseline (1294.685 us; speedup 1.0000x reference)
//
#include <hip/hip_runtime.h>
#include <math.h>

// Problem constants: B=8, L=512, D=1024, H=16, C=4, Dk=64
#define BB 8
#define LL 512
#define DD 1024
#define HH 16
#define CC 4
#define DK 64
#define NEG_DPI 201.06192982974676f   // 64 * pi

typedef __attribute__((ext_vector_type(8))) short short8;     // MFMA A/B frag (8 bf16)
typedef __attribute__((ext_vector_type(4))) float floatx4;    // MFMA C/D frag
typedef __attribute__((ext_vector_type(8))) unsigned short u16x8;
typedef __attribute__((ext_vector_type(4))) unsigned short u16x4;

// ---------------- helpers ----------------
__device__ inline float block_sum256(float v, float* s_red) {
    int t = threadIdx.x;
    s_red[t] = v; __syncthreads();
    for (int off = 128; off > 0; off >>= 1) {
        if (t < off) s_red[t] += s_red[t + off];
        __syncthreads();
    }
    float r = s_red[0]; __syncthreads();
    return r;
}
__device__ inline float block_max256(float v, float* s_red) {
    int t = threadIdx.x;
    s_red[t] = v; __syncthreads();
    for (int off = 128; off > 0; off >>= 1) {
        if (t < off) s_red[t] = fmaxf(s_red[t], s_red[t + off]);
        __syncthreads();
    }
    float r = s_red[0]; __syncthreads();
    return r;
}
__device__ inline unsigned int fenc(float f) {
    unsigned int b = __float_as_uint(f);
    return (b & 0x80000000u) ? ~b : (b | 0x80000000u);
}
__device__ inline float fdec(unsigned int u) {
    return (u & 0x80000000u) ? __uint_as_float(u ^ 0x80000000u) : __uint_as_float(~u);
}
__device__ inline unsigned short f2bf(float x) {   // RNE fp32 -> bf16
    unsigned int u = __float_as_uint(x);
    return (unsigned short)((u + 0x7FFFu + ((u >> 16) & 1u)) >> 16);
}
__device__ inline float bf2f(unsigned short h) {
    return __uint_as_float((unsigned int)h << 16);
}

// ---------------- fp32 -> bf16 hi/lo split (elementwise) ----------------
__global__ __launch_bounds__(256)
void convert_hilo(const float* __restrict__ x, unsigned short* __restrict__ hh,
                  unsigned short* __restrict__ ll) {
    int i = blockIdx.x * 256 + threadIdx.x;     // float4 unit
    float4 v = ((const float4*)x)[i];
    u16x4 h, l;
    float c[4] = {v.x, v.y, v.z, v.w};
#pragma unroll
    for (int j = 0; j < 4; j++) {
        unsigned short hb = f2bf(c[j]);
        h[j] = hb;
        l[j] = f2bf(c[j] - bf2f(hb));
    }
    ((u16x4*)hh)[i] = h;
    ((u16x4*)ll)[i] = l;
}

// ---------------- weight transpose + hi/lo convert: W[K][N] -> Wt[N][K] ----------------
__global__ __launch_bounds__(256)
void wconv_kernel(const float* __restrict__ W, unsigned short* __restrict__ Th,
                  unsigned short* __restrict__ Tl) {
    __shared__ float tile[64][65];
    int t = threadIdx.x;
    int n0 = blockIdx.x * 64, k0 = blockIdx.y * 64;
    int r = t >> 4, c4 = (t & 15) * 4;
#pragma unroll
    for (int rr = 0; rr < 64; rr += 16) {
        float4 v = *(const float4*)&W[(size_t)(k0 + r + rr) * DD + n0 + c4];
        tile[r + rr][c4 + 0] = v.x; tile[r + rr][c4 + 1] = v.y;
        tile[r + rr][c4 + 2] = v.z; tile[r + rr][c4 + 3] = v.w;
    }
    __syncthreads();
    int rn = t >> 2, kg = (t & 3) * 16;
    u16x8 oh[2], ol[2];
#pragma unroll
    for (int j = 0; j < 16; j++) {
        float x = tile[kg + j][rn];
        unsigned short hb = f2bf(x);
        oh[j >> 3][j & 7] = hb;
        ol[j >> 3][j & 7] = f2bf(x - bf2f(hb));
    }
    size_t o = (size_t)(n0 + rn) * DD + k0 + kg;
    *(u16x8*)&Th[o] = oh[0]; *(u16x8*)&Th[o + 8] = oh[1];
    *(u16x8*)&Tl[o] = ol[0]; *(u16x8*)&Tl[o + 8] = ol[1];
}

// ---------------- split-bf16 MFMA GEMM: C = A @ Wt^T + bias; optional hi/lo output ----------------
__global__ __launch_bounds__(256)
void mfma_gemm_bias(const unsigned short* __restrict__ Ah, const unsigned short* __restrict__ Al,
                    const unsigned short* __restrict__ Bh, const unsigned short* __restrict__ Bl,
                    const float* __restrict__ bias, float* __restrict__ C,
                    unsigned short* __restrict__ Ch, unsigned short* __restrict__ Cl) {
    __shared__ unsigned short sAh[128 * 32];
    __shared__ unsigned short sAl[128 * 32];
    __shared__ unsigned short sBh[128 * 32];
    __shared__ unsigned short sBl[128 * 32];
    int t = threadIdx.x;
    int n0 = blockIdx.x * 128, m0 = blockIdx.y * 128;
    int lane = t & 63, w = t >> 6;
    int wm = w >> 1, wn = w & 1;
    int lm = lane & 15, quad = lane >> 4;
    int srow = t >> 1, sk = (t & 1) * 16;

    const unsigned short* gAh = Ah + (size_t)(m0 + srow) * DD + sk;
    const unsigned short* gAl = Al + (size_t)(m0 + srow) * DD + sk;
    const unsigned short* gBh = Bh + (size_t)(n0 + srow) * DD + sk;
    const unsigned short* gBl = Bl + (size_t)(n0 + srow) * DD + sk;
    unsigned short* wAh = &sAh[srow * 32 + sk];
    unsigned short* wAl = &sAl[srow * 32 + sk];
    unsigned short* wBh = &sBh[srow * 32 + sk];
    unsigned short* wBl = &sBl[srow * 32 + sk];

    floatx4 acc[4][4] = {};

    for (int kt = 0; kt < 32; kt++) {
        int kb = kt * 32;
        u16x8 a0 = *(const u16x8*)(gAh + kb);
        u16x8 a1 = *(const u16x8*)(gAh + kb + 8);
        u16x8 a2 = *(const u16x8*)(gAl + kb);
        u16x8 a3 = *(const u16x8*)(gAl + kb + 8);
        u16x8 b0 = *(const u16x8*)(gBh + kb);
        u16x8 b1 = *(const u16x8*)(gBh + kb + 8);
        u16x8 b2 = *(const u16x8*)(gBl + kb);
        u16x8 b3 = *(const u16x8*)(gBl + kb + 8);
        __syncthreads();
        *(u16x8*)(wAh) = a0; *(u16x8*)(wAh + 8) = a1;
        *(u16x8*)(wAl) = a2; *(u16x8*)(wAl + 8) = a3;
        *(u16x8*)(wBh) = b0; *(u16x8*)(wBh + 8) = b1;
        *(u16x8*)(wBl) = b2; *(u16x8*)(wBl + 8) = b3;
        __syncthreads();

        short8 bh[4], bl[4];
#pragma unroll
        for (int j = 0; j < 4; j++) {
            int nb = (wn * 64 + j * 16 + lm) * 32 + quad * 8;
            bh[j] = *(const short8*)&sBh[nb];
            bl[j] = *(const short8*)&sBl[nb];
        }
#pragma unroll
        for (int i = 0; i < 4; i++) {
            int ab = (wm * 64 + i * 16 + lm) * 32 + quad * 8;
            short8 ah = *(const short8*)&sAh[ab];
            short8 al = *(const short8*)&sAl[ab];
#pragma unroll
            for (int j = 0; j < 4; j++) {
                acc[i][j] = __builtin_amdgcn_mfma_f32_16x16x32_bf16(ah, bh[j], acc[i][j], 0, 0, 0);
                acc[i][j] = __builtin_amdgcn_mfma_f32_16x16x32_bf16(ah, bl[j], acc[i][j], 0, 0, 0);
                acc[i][j] = __builtin_amdgcn_mfma_f32_16x16x32_bf16(al, bh[j], acc[i][j], 0, 0, 0);
            }
        }
    }
#pragma unroll
    for (int i = 0; i < 4; i++) {
#pragma unroll
        for (int j = 0; j < 4; j++) {
            int n = n0 + wn * 64 + j * 16 + lm;
            float bv = bias[n];
#pragma unroll
            for (int r = 0; r < 4; r++) {
                int m = m0 + wm * 64 + i * 16 + quad * 4 + r;
                size_t idx = (size_t)m * DD + n;
                float val = acc[i][j][r] + bv;
                C[idx] = val;
                if (Ch) {
                    unsigned short hb = f2bf(val);
                    Ch[idx] = hb;
                    Cl[idx] = f2bf(val - bf2f(hb));
                }
            }
        }
    }
}

// ---------------- V transpose to Vt[d][l] (bf16, one of hi/lo per call) ----------------
__global__ __launch_bounds__(256)
void vt_prep(const unsigned short* __restrict__ src, unsigned short* __restrict__ dst) {
    __shared__ unsigned short tile[128 * 68];
    int t = threadIdx.x;
    int l0 = blockIdx.x * 128, h = blockIdx.y, b = blockIdx.z;
#pragma unroll
    for (int i = 0; i < 8; i++) {
        int u = t + i * 256;                 // ushort4 units
        int l = u >> 4, c4 = (u & 15) * 4;
        u16x4 v4 = *(const u16x4*)&src[((size_t)(b * LL + l0 + l)) * DD + h * DK + c4];
        tile[l * 68 + c4 + 0] = v4[0]; tile[l * 68 + c4 + 1] = v4[1];
        tile[l * 68 + c4 + 2] = v4[2]; tile[l * 68 + c4 + 3] = v4[3];
    }
    __syncthreads();
    size_t ob = ((size_t)(b * HH + h)) * DK * LL;
#pragma unroll
    for (int i = 0; i < 8; i++) {
        int u = t + i * 256;                 // ushort4 units along l
        int d = u >> 5, lq = (u & 31) * 4;
        u16x4 o;
#pragma unroll
        for (int j = 0; j < 4; j++) o[j] = tile[(lq + j) * 68 + d];
        *(u16x4*)&dst[ob + (size_t)d * LL + l0 + lq] = o;
    }
}

// ---------------- alv = (A @ Wp + bias) transposed to (B,H,L) ----------------
__global__ __launch_bounds__(256)
void alv_gemm(const float* __restrict__ A, const float* __restrict__ Wp,
              const float* __restrict__ bias, float* __restrict__ alv) {
    __shared__ float As[16][65];
    __shared__ float Ws[64][17];
    int t = threadIdx.x;
    int m0 = blockIdx.x * 16;
    int r = t >> 4, hh = t & 15;
    float acc = 0.f;
    for (int kt = 0; kt < 16; kt++) {
        __syncthreads();
#pragma unroll
        for (int i = 0; i < 4; i++) {
            int e = t + i * 256;
            int rr = e >> 6, kk = e & 63;
            As[rr][kk] = A[(size_t)(m0 + rr) * DD + kt * 64 + kk];
        }
#pragma unroll
        for (int i = 0; i < 4; i++) {
            int e = t + i * 256;
            int kk = e >> 4, h2 = e & 15;
            Ws[kk][h2] = Wp[(size_t)(kt * 64 + kk) * HH + h2];
        }
        __syncthreads();
#pragma unroll
        for (int kk = 0; kk < 64; kk++) acc += As[r][kk] * Ws[kk][hh];
    }
    int m = m0 + r;
    int b = m >> 9, l = m & 511;
    alv[(size_t)(b * HH + hh) * LL + l] = acc + bias[hh];
}

// ---------------- clustering ----------------
__global__ __launch_bounds__(256)
void cluster_kernel(const float* __restrict__ zsrc, const float* __restrict__ alv,
                    const float* __restrict__ mu, const float* __restrict__ logvar,
                    const float* __restrict__ logprior,
                    float* __restrict__ cp_out, float* __restrict__ lpdf_out,
                    unsigned int* __restrict__ maxenc, float* __restrict__ kl_out,
                    int isHead) {
    __shared__ float s_mu[CC * DK], s_iv[CC * DK], s_lv[CC * DK];
    __shared__ float s_slv[CC], s_siv[CC], s_lp[CC];
    __shared__ float s_red[256];
    int t = threadIdx.x;
    int tile = blockIdx.x & 1;
    int bh = blockIdx.x >> 1;
    int h = bh & (HH - 1), b = bh >> 4;
    int hm = isHead ? 0 : h;

    {
        float m = mu[hm * CC * DK + t];
        float lv = logvar[hm * CC * DK + t];
        s_mu[t] = m; s_lv[t] = lv; s_iv[t] = expf(-lv);
    }
    __syncthreads();
    if (t < CC) {
        float slv = 0.f, siv = 0.f;
        for (int d = 0; d < DK; d++) { slv += s_lv[t * DK + d]; siv += s_iv[t * DK + d]; }
        s_slv[t] = slv; s_siv[t] = siv;
    }
    if (t == CC) {
        float x[CC];
        float m = -1e30f;
        for (int c = 0; c < CC; c++) { x[c] = logprior[hm * CC + c]; m = fmaxf(m, x[c]); }
        float se = 0.f;
        for (int c = 0; c < CC; c++) se += expf(x[c] - m);
        float lse = m + logf(se);
        for (int c = 0; c < CC; c++) s_lp[c] = x[c] - lse;
    }
    __syncthreads();

    int l = tile * 256 + t;
    const float* zp = zsrc + ((size_t)(b * LL + l)) * DD + h * DK;
    float acc[CC] = {0.f, 0.f, 0.f, 0.f};
    for (int d = 0; d < DK; d += 4) {
        float4 z4 = *(const float4*)(zp + d);
#pragma unroll
        for (int c = 0; c < CC; c++) {
            float d0 = z4.x - s_mu[c * DK + d];     acc[c] += d0 * d0 * s_iv[c * DK + d];
            float d1 = z4.y - s_mu[c * DK + d + 1]; acc[c] += d1 * d1 * s_iv[c * DK + d + 1];
            float d2 = z4.z - s_mu[c * DK + d + 2]; acc[c] += d2 * d2 * s_iv[c * DK + d + 2];
            float d3 = z4.w - s_mu[c * DK + d + 3]; acc[c] += d3 * d3 * s_iv[c * DK + d + 3];
        }
    }
    float lpdf[CC];
#pragma unroll
    for (int c = 0; c < CC; c++)
        lpdf[c] = -0.5f * acc[c] - 0.5f * s_slv[c] - NEG_DPI + s_lp[c];
    float m = fmaxf(fmaxf(lpdf[0], lpdf[1]), fmaxf(lpdf[2], lpdf[3]));
    float se = 0.f;
#pragma unroll
    for (int c = 0; c < CC; c++) se += expf(lpdf[c] - m);
    float lse = m + logf(se);
    float lprob[CC], cpv[CC];
    size_t idx = ((size_t)(bh * LL + l)) * CC;
#pragma unroll
    for (int c = 0; c < CC; c++) {
        lprob[c] = lpdf[c] - lse;
        cpv[c] = expf(lprob[c]);
        cp_out[idx + c] = cpv[c];
    }
    if (isHead) {
#pragma unroll
        for (int c = 0; c < CC; c++) lpdf_out[idx + c] = lpdf[c];
    }
    float alvv = alv[(size_t)bh * LL + l];
    float avar = expf(alvv);
    float t1 = 0.f, t2 = 0.f;
#pragma unroll
    for (int c = 0; c < CC; c++) {
        t1 += expf(s_lp[c]) * (s_lp[c] - lprob[c]);
        t2 += cpv[c] * (acc[c] + avar * s_siv[c] + s_slv[c]);
    }
    float klv = t1 + 0.5f * t2 - 0.5f * (float)DK * (1.0f + alvv);
    float tot = block_sum256(klv, s_red);
    if (t == 0) atomicAdd(kl_out + b, tot * (1.0f / (HH * LL)));
    if (isHead) {
        float mt = block_max256(m, s_red);
        if (t == 0) atomicMax(maxenc, fenc(mt));
    }
}

// ---------------- pair stats: div loss (+ head: diag log_softmax(aff)) ----------------
__global__ __launch_bounds__(256)
void pairstats_kernel(const float* __restrict__ cp, float* __restrict__ div_out,
                      float* __restrict__ mi_out, int isHead) {
    __shared__ float s_cp[LL * CC];
    __shared__ float s_red[256];
    int t = threadIdx.x;
    int bh = blockIdx.x;
    int b = bh >> 4;
    const float* base = cp + (size_t)bh * LL * CC;
#pragma unroll
    for (int i = 0; i < 8; i++) s_cp[t + i * 256] = base[t + i * 256];
    __syncthreads();
    float divacc = 0.f, diagacc = 0.f;
    for (int qi = 0; qi < 2; qi++) {
        int q = t + qi * 256;
        float c0 = s_cp[q * 4 + 0], c1 = s_cp[q * 4 + 1], c2 = s_cp[q * 4 + 2], c3 = s_cp[q * 4 + 3];
        float m = -1e30f, s = 0.f, selfdot = 0.f;
        for (int k = 0; k < LL; k++) {
            float dot = c0 * s_cp[k * 4 + 0] + c1 * s_cp[k * 4 + 1] + c2 * s_cp[k * 4 + 2] + c3 * s_cp[k * 4 + 3];
            float del = (k == q) ? 1.f : 0.f;
            float dd = dot - del;
            divacc += dd * dd * (del * 1.25f + (1.f - del) * 0.75f);
            if (isHead) {
                if (dot > m) { s = s * expf(m - dot) + 1.f; m = dot; }
                else         { s += expf(dot - m); }
                if (k == q) selfdot = dot;
            }
        }
        if (isHead) diagacc += selfdot - (m + logf(s));
    }
    float dtot = block_sum256(divacc, s_red);
    if (t == 0) atomicAdd(div_out + b, dtot * (1.0f / ((float)HH * LL * LL)));
    if (isHead) {
        float gtot = block_sum256(diagacc, s_red);
        if (t == 0) atomicAdd(mi_out + b, -gtot * (1.0f / (HH * LL)));
    }
}

// ---------------- attention v3: MFMA, one (b,h,16-row q-tile) per block ----------------
// Phase1: S = (Q Kt)/8 via 3-pass split-bf16 MFMA (frags direct from global/L2).
// Phase2: softmax+mask+renorm; atomicAdd P/H to attn_out; P -> bf16 hi/lo in LDS (unioned with S).
// Phase3: ctx = P V via 3-pass MFMA against pre-transposed Vt.
__global__ __launch_bounds__(256)
void attn3_kernel(const unsigned short* __restrict__ qoh, const unsigned short* __restrict__ qol,
                  const unsigned short* __restrict__ koh, const unsigned short* __restrict__ kol,
                  const unsigned short* __restrict__ vth, const unsigned short* __restrict__ vtl,
                  const float* __restrict__ cpq,
                  float* __restrict__ ctxf, float* __restrict__ attn_out) {
    // union: S fp32 [16][516] (33024 B)  /  Ph,Pl bf16 [16][520] each (33280 B)
    __shared__ __align__(16) char sbuf[33280];
    __shared__ float s_cp[LL * CC];    // 8 KB
    __shared__ float s_inv[16];
    float* S = (float*)sbuf;
    unsigned short* Ph = (unsigned short*)sbuf;
    unsigned short* Pl = Ph + 16 * 520;

    int t = threadIdx.x;
    int qt = blockIdx.x, h = blockIdx.y, b = blockIdx.z;
    int q0 = qt * 16;
    int lane = t & 63, w = t >> 6;
    int lm = lane & 15, quad = lane >> 4;
    int bh = b * HH + h;

    // stage cp rows for this (b,h)
    {
        const float* cpb = cpq + (size_t)bh * LL * CC;
#pragma unroll
        for (int i = 0; i < 2; i++) {
            int e = t + i * 256;                  // float4 unit
            *(float4*)&s_cp[e * 4] = *(const float4*)&cpb[e * 4];
        }
    }

    // ---- phase 1: scores ----
    size_t qbase = ((size_t)(b * LL + q0 + lm)) * DD + h * DK + quad * 8;
    short8 qah0 = *(const short8*)(qoh + qbase);
    short8 qah1 = *(const short8*)(qoh + qbase + 32);
    short8 qal0 = *(const short8*)(qol + qbase);
    short8 qal1 = *(const short8*)(qol + qbase + 32);

    floatx4 sa[8] = {};
#pragma unroll
    for (int j = 0; j < 8; j++) {
        int n0 = w * 128 + j * 16;
        size_t kbase = ((size_t)(b * LL + n0 + lm)) * DD + h * DK + quad * 8;
        short8 kbh0 = *(const short8*)(koh + kbase);
        short8 kbh1 = *(const short8*)(koh + kbase + 32);
        short8 kbl0 = *(const short8*)(kol + kbase);
        short8 kbl1 = *(const short8*)(kol + kbase + 32);
        sa[j] = __builtin_amdgcn_mfma_f32_16x16x32_bf16(qah0, kbh0, sa[j], 0, 0, 0);
        sa[j] = __builtin_amdgcn_mfma_f32_16x16x32_bf16(qah1, kbh1, sa[j], 0, 0, 0);
        sa[j] = __builtin_amdgcn_mfma_f32_16x16x32_bf16(qah0, kbl0, sa[j], 0, 0, 0);
        sa[j] = __builtin_amdgcn_mfma_f32_16x16x32_bf16(qah1, kbl1, sa[j], 0, 0, 0);
        sa[j] = __builtin_amdgcn_mfma_f32_16x16x32_bf16(qal0, kbh0, sa[j], 0, 0, 0);
        sa[j] = __builtin_amdgcn_mfma_f32_16x16x32_bf16(qal1, kbh1, sa[j], 0, 0, 0);
    }
    __syncthreads();   // s_cp staged; S buffer free
#pragma unroll
    for (int j = 0; j < 8; j++) {
        int kc = w * 128 + j * 16 + lm;
#pragma unroll
        for (int r = 0; r < 4; r++)
            S[(quad * 4 + r) * 516 + kc] = sa[j][r] * 0.125f;
    }
    __syncthreads();

    // ---- phase 2a: softmax + mask + renorm factor (16 lanes per row) ----
    {
        int r = t >> 4, ln = t & 15;
        float m = -1e30f;
        for (int k = ln; k < LL; k += 16) m = fmaxf(m, S[r * 516 + k]);
#pragma unroll
        for (int off = 8; off > 0; off >>= 1) m = fmaxf(m, __shfl_xor(m, off, 16));
        float4 cq = *(float4*)&s_cp[(q0 + r) * 4];
        float Z = 0.f, Sm = 0.f;
        for (int k = ln; k < LL; k += 16) {
            float e = expf(S[r * 516 + k] - m);
            float4 ck = *(float4*)&s_cp[k * 4];
            float mask = cq.x * ck.x + cq.y * ck.y + cq.z * ck.z + cq.w * ck.w;
            float a = e * mask;
            Z += e; Sm += a;
            S[r * 516 + k] = a;
        }
#pragma unroll
        for (int off = 8; off > 0; off >>= 1) {
            Z += __shfl_xor(Z, off, 16);
            Sm += __shfl_xor(Sm, off, 16);
        }
        if (ln == 0) s_inv[r] = 1.f / (Sm + 1e-6f * Z);
    }
    __syncthreads();

    // ---- phase 2b: normalize into regs + atomic attn mean ----
    float4 pv[8];
#pragma unroll
    for (int i = 0; i < 8; i++) {
        int e = t + i * 256;                 // float4 unit, 2048 total
        int r2 = e >> 7, k4 = (e & 127) * 4;
        float4 p = *(float4*)&S[r2 * 516 + k4];
        float inv = s_inv[r2];
        p.x *= inv; p.y *= inv; p.z *= inv; p.w *= inv;
        pv[i] = p;
        float* ao = attn_out + ((size_t)(b * LL + q0 + r2)) * LL + k4;
        const float sc = 1.0f / (float)HH;
        atomicAdd(ao + 0, p.x * sc);
        atomicAdd(ao + 1, p.y * sc);
        atomicAdd(ao + 2, p.z * sc);
        atomicAdd(ao + 3, p.w * sc);
    }
    __syncthreads();   // all reads of S done; overwrite with Ph/Pl
#pragma unroll
    for (int i = 0; i < 8; i++) {
        int e = t + i * 256;
        int r2 = e >> 7, k4 = (e & 127) * 4;
        float c[4] = {pv[i].x, pv[i].y, pv[i].z, pv[i].w};
        u16x4 hv, lv;
#pragma unroll
        for (int j = 0; j < 4; j++) {
            unsigned short hb = f2bf(c[j]);
            hv[j] = hb;
            lv[j] = f2bf(c[j] - bf2f(hb));
        }
        *(u16x4*)&Ph[r2 * 520 + k4] = hv;
        *(u16x4*)&Pl[r2 * 520 + k4] = lv;
    }
    __syncthreads();

    // ---- phase 3: ctx = P @ V via Vt ----
    int dn = w * 16 + lm;
    const unsigned short* vrh = vth + ((size_t)bh * DK + dn) * LL;
    const unsigned short* vrl = vtl + ((size_t)bh * DK + dn) * LL;
    floatx4 ca = {};
#pragma unroll
    for (int kc = 0; kc < 16; kc++) {
        int kb = kc * 32 + quad * 8;
        short8 pah = *(const short8*)&Ph[lm * 520 + kb];
        short8 pal = *(const short8*)&Pl[lm * 520 + kb];
        short8 vbh = *(const short8*)(vrh + kb);
        short8 vbl = *(const short8*)(vrl + kb);
        ca = __builtin_amdgcn_mfma_f32_16x16x32_bf16(pah, vbh, ca, 0, 0, 0);
        ca = __builtin_amdgcn_mfma_f32_16x16x32_bf16(pah, vbl, ca, 0, 0, 0);
        ca = __builtin_amdgcn_mfma_f32_16x16x32_bf16(pal, vbh, ca, 0, 0, 0);
    }
#pragma unroll
    for (int r = 0; r < 4; r++)
        ctxf[((size_t)(b * LL + q0 + quad * 4 + r)) * DD + h * DK + dn] = ca[r];
}

// ---------------- MI: pdf + wsum ----------------
__global__ __launch_bounds__(256)
void wsum_kernel(const float* __restrict__ lpdf, const float* __restrict__ cp,
                 const unsigned int* __restrict__ maxenc,
                 float* __restrict__ pdf_out, float* __restrict__ wsum_out) {
    __shared__ float s_red[256];
    int t = threadIdx.x;
    int bh = blockIdx.x;
    float M = fdec(*maxenc);
    float a[CC] = {0.f, 0.f, 0.f, 0.f};
    for (int li = 0; li < 2; li++) {
        int l = t + li * 256;
        size_t idx = ((size_t)bh * LL + l) * CC;
        float p0 = expf(lpdf[idx + 0] - M);
        float p1 = expf(lpdf[idx + 1] - M);
        float p2 = expf(lpdf[idx + 2] - M);
        float p3 = expf(lpdf[idx + 3] - M);
        float pd = p0 + p1 + p2 + p3;
        pdf_out[(size_t)bh * LL + l] = pd;
        a[0] += cp[idx + 0] * pd; a[1] += cp[idx + 1] * pd;
        a[2] += cp[idx + 2] * pd; a[3] += cp[idx + 3] * pd;
    }
#pragma unroll
    for (int c = 0; c < CC; c++) {
        float tot = block_sum256(a[c], s_red);
        if (t == 0) wsum_out[bh * CC + c] = tot;
    }
}

// ---------------- MI: pairwise head overlap ----------------
__global__ __launch_bounds__(256)
void mi_kernel(const float* __restrict__ cp, const float* __restrict__ pdf,
               const float* __restrict__ wsum, float* __restrict__ mi_out) {
    __shared__ float s_q[HH * CC];
    __shared__ float s_c[HH * CC];
    __shared__ float s_red[256];
    int t = threadIdx.x;
    int b = blockIdx.x >> 9;
    int l = blockIdx.x & 511;
    if (t < HH * CC) {
        int i = t >> 2, c = t & 3;
        float cpv = cp[((size_t)(b * HH + i) * LL + l) * CC + c];
        s_c[t] = cpv;
        float w = cpv * pdf[(size_t)(b * HH + i) * LL + l];
        float ws = wsum[(b * HH + i) * CC + c];
        s_q[t] = w / fmaxf(ws, 1e-6f);
    }
    __syncthreads();
    int i = t >> 4, j = t & 15;
    float sdot = 0.f;
#pragma unroll
    for (int c = 0; c < CC; c++) sdot += s_q[i * 4 + c] * s_c[j * 4 + c];
    float mi_p = fminf(sdot, 1.f);
    float val = (i != j) ? logf(1.f - mi_p + 1e-6f) : 0.f;
    float tot = block_sum256(val, s_red);
    if (t == 0) atomicAdd(mi_out + b, -10.f * tot * (1.0f / ((float)LL * HH * HH)));
}

// ---------------- launcher ----------------
extern "C" void kernel_launch(void* const* d_in, const int* in_sizes, int n_in,
                              void* d_out, int out_size, void* d_ws, size_t ws_size,
                              hipStream_t stream) {
    (void)in_sizes; (void)n_in; (void)out_size; (void)ws_size;
    const float* query  = (const float*)d_in[0];
    const float* key    = (const float*)d_in[1];
    const float* value  = (const float*)d_in[2];
    const float* Wq     = (const float*)d_in[3];
    const float* bq     = (const float*)d_in[4];
    const float* Wk     = (const float*)d_in[5];
    const float* bk     = (const float*)d_in[6];
    const float* Wv     = (const float*)d_in[7];
    const float* bv     = (const float*)d_in[8];
    const float* Wo     = (const float*)d_in[9];
    const float* bo     = (const float*)d_in[10];
    const float* Wsem   = (const float*)d_in[11];
    const float* bsem   = (const float*)d_in[12];
    const float* Whead  = (const float*)d_in[13];
    const float* bhead  = (const float*)d_in[14];
    const float* tokmu  = (const float*)d_in[15];
    const float* toklv  = (const float*)d_in[16];
    const float* toklp  = (const float*)d_in[17];
    const float* headmu = (const float*)d_in[18];
    const float* headlv = (const float*)d_in[19];
    const float* headlp = (const float*)d_in[20];

    float* ws   = (float*)d_ws;
    const size_t NBLD = (size_t)BB * LL * DD;      // 4194304
    float* q    = ws;
    float* k    = ws + NBLD;
    float* v    = ws + 2 * NBLD;
    float* ctxf = ws + 3 * NBLD;
    float* alvq = ws + 4 * NBLD;
    float* alvh = alvq + (size_t)BB * HH * LL;
    float* cpq  = alvh + (size_t)BB * HH * LL;
    float* cph  = cpq + (size_t)BB * HH * LL * CC;
    float* lpdfh= cph + (size_t)BB * HH * LL * CC;
    float* pdfb = lpdfh + (size_t)BB * HH * LL * CC;
    float* wsumb= pdfb + (size_t)BB * HH * LL;
    unsigned int* maxenc = (unsigned int*)(wsumb + (size_t)BB * HH * CC);

    // bf16 scratch (ushort)
    unsigned short* us = (unsigned short*)(maxenc + 4);
    const size_t WSZ = (size_t)DD * DD;            // 1048576
    unsigned short* ist_h = us;                    // input staging (reused serially)
    unsigned short* ist_l = ist_h + NBLD;
    unsigned short* qoh = ist_l + NBLD;
    unsigned short* qol = qoh + NBLD;
    unsigned short* koh = qol + NBLD;
    unsigned short* kol = koh + NBLD;
    unsigned short* voh = kol + NBLD;
    unsigned short* vol = voh + NBLD;
    unsigned short* vth = vol + NBLD;              // Vt[d][l] per (b,h)
    unsigned short* vtl = vth + NBLD;
    unsigned short* wqh = vtl + NBLD;
    unsigned short* wql = wqh + WSZ;
    unsigned short* wkh = wql + WSZ;
    unsigned short* wkl = wkh + WSZ;
    unsigned short* wvh = wkl + WSZ;
    unsigned short* wvl = wvh + WSZ;
    unsigned short* woh = wvl + WSZ;
    unsigned short* wol = woh + WSZ;

    float* out      = (float*)d_out;
    float* attn_out = out + NBLD;
    float* kl_out   = attn_out + (size_t)BB * LL * LL;
    float* div_out  = kl_out + BB;
    float* mi_out   = div_out + BB;

    hipMemsetAsync(kl_out, 0, 3 * BB * sizeof(float), stream);
    hipMemsetAsync(attn_out, 0, (size_t)BB * LL * LL * sizeof(float), stream);
    hipMemsetAsync(maxenc, 0, sizeof(unsigned int), stream);

    dim3 wg(16, 16);
    wconv_kernel<<<wg, 256, 0, stream>>>(Wq, wqh, wql);
    wconv_kernel<<<wg, 256, 0, stream>>>(Wk, wkh, wkl);
    wconv_kernel<<<wg, 256, 0, stream>>>(Wv, wvh, wvl);
    wconv_kernel<<<wg, 256, 0, stream>>>(Wo, woh, wol);

    dim3 gg(DD / 128, BB * LL / 128);  // (8, 32)
    convert_hilo<<<NBLD / 1024, 256, 0, stream>>>(query, ist_h, ist_l);
    mfma_gemm_bias<<<gg, 256, 0, stream>>>(ist_h, ist_l, wqh, wql, bq, q, qoh, qol);
    convert_hilo<<<NBLD / 1024, 256, 0, stream>>>(key, ist_h, ist_l);
    mfma_gemm_bias<<<gg, 256, 0, stream>>>(ist_h, ist_l, wkh, wkl, bk, k, koh, kol);
    convert_hilo<<<NBLD / 1024, 256, 0, stream>>>(value, ist_h, ist_l);
    mfma_gemm_bias<<<gg, 256, 0, stream>>>(ist_h, ist_l, wvh, wvl, bv, v, voh, vol);

    dim3 vtg(LL / 128, HH, BB);
    vt_prep<<<vtg, 256, 0, stream>>>(voh, vth);
    vt_prep<<<vtg, 256, 0, stream>>>(vol, vtl);

    alv_gemm<<<BB * LL / 16, 256, 0, stream>>>(q, Wsem, bsem, alvq);
    cluster_kernel<<<BB * HH * 2, 256, 0, stream>>>(q, alvq, tokmu, toklv, toklp,
                                                    cpq, nullptr, nullptr, kl_out, 0);
    pairstats_kernel<<<BB * HH, 256, 0, stream>>>(cpq, div_out, nullptr, 0);

    attn3_kernel<<<dim3(LL / 16, HH, BB), 256, 0, stream>>>(
        qoh, qol, koh, kol, vth, vtl, cpq, ctxf, attn_out);

    convert_hilo<<<NBLD / 1024, 256, 0, stream>>>(ctxf, ist_h, ist_l);
    alv_gemm<<<BB * LL / 16, 256, 0, stream>>>(ctxf, Whead, bhead, alvh);
    cluster_kernel<<<BB * HH * 2, 256, 0, stream>>>(ctxf, alvh, headmu, headlv, headlp,
                                                    cph, lpdfh, maxenc, kl_out, 1);
    pairstats_kernel<<<BB * HH, 256, 0, stream>>>(cph, div_out, mi_out, 1);
    wsum_kernel<<<BB * HH, 256, 0, stream>>>(lpdfh, cph, maxenc, pdfb, wsumb);
    mi_kernel<<<BB * LL, 256, 0, stream>>>(cph, pdfb, wsumb, mi_out);
    mfma_gemm_bias<<<gg, 256, 0, stream>>>(ist_h, ist_l, woh, wol, bo, out, nullptr, nullptr);
}

// Round 5
// 979.835 us; speedup vs baseline: 1.3213x; 1.3213x over previous
//
#include <hip/hip_runtime.h>
#include <math.h>

// Problem constants: B=8, L=512, D=1024, H=16, C=4, Dk=64
#define BB 8
#define LL 512
#define DD 1024
#define HH 16
#define CC 4
#define DK 64
#define NEG_DPI 201.06192982974676f   // 64 * pi

typedef __attribute__((ext_vector_type(8))) short short8;     // MFMA A/B frag (8 bf16)
typedef __attribute__((ext_vector_type(4))) float floatx4;    // MFMA C/D frag
typedef __attribute__((ext_vector_type(8))) unsigned short u16x8;
typedef __attribute__((ext_vector_type(4))) unsigned short u16x4;

// ---------------- helpers ----------------
__device__ inline float block_sum256(float v, float* s_red) {
    int t = threadIdx.x;
    s_red[t] = v; __syncthreads();
    for (int off = 128; off > 0; off >>= 1) {
        if (t < off) s_red[t] += s_red[t + off];
        __syncthreads();
    }
    float r = s_red[0]; __syncthreads();
    return r;
}
__device__ inline float block_max256(float v, float* s_red) {
    int t = threadIdx.x;
    s_red[t] = v; __syncthreads();
    for (int off = 128; off > 0; off >>= 1) {
        if (t < off) s_red[t] = fmaxf(s_red[t], s_red[t + off]);
        __syncthreads();
    }
    float r = s_red[0]; __syncthreads();
    return r;
}
__device__ inline unsigned int fenc(float f) {
    unsigned int b = __float_as_uint(f);
    return (b & 0x80000000u) ? ~b : (b | 0x80000000u);
}
__device__ inline float fdec(unsigned int u) {
    return (u & 0x80000000u) ? __uint_as_float(u ^ 0x80000000u) : __uint_as_float(~u);
}
__device__ inline unsigned short f2bf(float x) {   // RNE fp32 -> bf16
    unsigned int u = __float_as_uint(x);
    return (unsigned short)((u + 0x7FFFu + ((u >> 16) & 1u)) >> 16);
}
__device__ inline float bf2f(unsigned short h) {
    return __uint_as_float((unsigned int)h << 16);
}

// ---------------- fp32 -> bf16 hi/lo split (elementwise) ----------------
__global__ __launch_bounds__(256)
void convert_hilo(const float* __restrict__ x, unsigned short* __restrict__ hh,
                  unsigned short* __restrict__ ll) {
    int i = blockIdx.x * 256 + threadIdx.x;     // float4 unit
    float4 v = ((const float4*)x)[i];
    u16x4 h, l;
    float c[4] = {v.x, v.y, v.z, v.w};
#pragma unroll
    for (int j = 0; j < 4; j++) {
        unsigned short hb = f2bf(c[j]);
        h[j] = hb;
        l[j] = f2bf(c[j] - bf2f(hb));
    }
    ((u16x4*)hh)[i] = h;
    ((u16x4*)ll)[i] = l;
}

// ---------------- weight transpose + hi/lo convert: W[K][N] -> Wt[N][K] ----------------
__global__ __launch_bounds__(256)
void wconv_kernel(const float* __restrict__ W, unsigned short* __restrict__ Th,
                  unsigned short* __restrict__ Tl) {
    __shared__ float tile[64][65];
    int t = threadIdx.x;
    int n0 = blockIdx.x * 64, k0 = blockIdx.y * 64;
    int r = t >> 4, c4 = (t & 15) * 4;
#pragma unroll
    for (int rr = 0; rr < 64; rr += 16) {
        float4 v = *(const float4*)&W[(size_t)(k0 + r + rr) * DD + n0 + c4];
        tile[r + rr][c4 + 0] = v.x; tile[r + rr][c4 + 1] = v.y;
        tile[r + rr][c4 + 2] = v.z; tile[r + rr][c4 + 3] = v.w;
    }
    __syncthreads();
    int rn = t >> 2, kg = (t & 3) * 16;
    u16x8 oh[2], ol[2];
#pragma unroll
    for (int j = 0; j < 16; j++) {
        float x = tile[kg + j][rn];
        unsigned short hb = f2bf(x);
        oh[j >> 3][j & 7] = hb;
        ol[j >> 3][j & 7] = f2bf(x - bf2f(hb));
    }
    size_t o = (size_t)(n0 + rn) * DD + k0 + kg;
    *(u16x8*)&Th[o] = oh[0]; *(u16x8*)&Th[o + 8] = oh[1];
    *(u16x8*)&Tl[o] = ol[0]; *(u16x8*)&Tl[o + 8] = ol[1];
}

// ---------------- split-bf16 MFMA GEMM: C = A @ Wt^T + bias; fp32 and/or hi-lo out ----------------
__global__ __launch_bounds__(256)
void mfma_gemm_bias(const unsigned short* __restrict__ Ah, const unsigned short* __restrict__ Al,
                    const unsigned short* __restrict__ Bh, const unsigned short* __restrict__ Bl,
                    const float* __restrict__ bias, float* __restrict__ C,
                    unsigned short* __restrict__ Ch, unsigned short* __restrict__ Cl) {
    __shared__ unsigned short sAh[128 * 32];
    __shared__ unsigned short sAl[128 * 32];
    __shared__ unsigned short sBh[128 * 32];
    __shared__ unsigned short sBl[128 * 32];
    int t = threadIdx.x;
    int n0 = blockIdx.x * 128, m0 = blockIdx.y * 128;
    int lane = t & 63, w = t >> 6;
    int wm = w >> 1, wn = w & 1;
    int lm = lane & 15, quad = lane >> 4;
    int srow = t >> 1, sk = (t & 1) * 16;

    const unsigned short* gAh = Ah + (size_t)(m0 + srow) * DD + sk;
    const unsigned short* gAl = Al + (size_t)(m0 + srow) * DD + sk;
    const unsigned short* gBh = Bh + (size_t)(n0 + srow) * DD + sk;
    const unsigned short* gBl = Bl + (size_t)(n0 + srow) * DD + sk;
    unsigned short* wAh = &sAh[srow * 32 + sk];
    unsigned short* wAl = &sAl[srow * 32 + sk];
    unsigned short* wBh = &sBh[srow * 32 + sk];
    unsigned short* wBl = &sBl[srow * 32 + sk];

    floatx4 acc[4][4] = {};

    for (int kt = 0; kt < 32; kt++) {
        int kb = kt * 32;
        u16x8 a0 = *(const u16x8*)(gAh + kb);
        u16x8 a1 = *(const u16x8*)(gAh + kb + 8);
        u16x8 a2 = *(const u16x8*)(gAl + kb);
        u16x8 a3 = *(const u16x8*)(gAl + kb + 8);
        u16x8 b0 = *(const u16x8*)(gBh + kb);
        u16x8 b1 = *(const u16x8*)(gBh + kb + 8);
        u16x8 b2 = *(const u16x8*)(gBl + kb);
        u16x8 b3 = *(const u16x8*)(gBl + kb + 8);
        __syncthreads();
        *(u16x8*)(wAh) = a0; *(u16x8*)(wAh + 8) = a1;
        *(u16x8*)(wAl) = a2; *(u16x8*)(wAl + 8) = a3;
        *(u16x8*)(wBh) = b0; *(u16x8*)(wBh + 8) = b1;
        *(u16x8*)(wBl) = b2; *(u16x8*)(wBl + 8) = b3;
        __syncthreads();

        short8 bh[4], bl[4];
#pragma unroll
        for (int j = 0; j < 4; j++) {
            int nb = (wn * 64 + j * 16 + lm) * 32 + quad * 8;
            bh[j] = *(const short8*)&sBh[nb];
            bl[j] = *(const short8*)&sBl[nb];
        }
#pragma unroll
        for (int i = 0; i < 4; i++) {
            int ab = (wm * 64 + i * 16 + lm) * 32 + quad * 8;
            short8 ah = *(const short8*)&sAh[ab];
            short8 al = *(const short8*)&sAl[ab];
#pragma unroll
            for (int j = 0; j < 4; j++) {
                acc[i][j] = __builtin_amdgcn_mfma_f32_16x16x32_bf16(ah, bh[j], acc[i][j], 0, 0, 0);
                acc[i][j] = __builtin_amdgcn_mfma_f32_16x16x32_bf16(ah, bl[j], acc[i][j], 0, 0, 0);
                acc[i][j] = __builtin_amdgcn_mfma_f32_16x16x32_bf16(al, bh[j], acc[i][j], 0, 0, 0);
            }
        }
    }
#pragma unroll
    for (int i = 0; i < 4; i++) {
#pragma unroll
        for (int j = 0; j < 4; j++) {
            int n = n0 + wn * 64 + j * 16 + lm;
            float bv = bias[n];
#pragma unroll
            for (int r = 0; r < 4; r++) {
                int m = m0 + wm * 64 + i * 16 + quad * 4 + r;
                size_t idx = (size_t)m * DD + n;
                float val = acc[i][j][r] + bv;
                if (C) C[idx] = val;
                if (Ch) {
                    unsigned short hb = f2bf(val);
                    Ch[idx] = hb;
                    Cl[idx] = f2bf(val - bf2f(hb));
                }
            }
        }
    }
}

// ---------------- V transpose to Vt[d][l] (bf16, one of hi/lo per call) ----------------
__global__ __launch_bounds__(256)
void vt_prep(const unsigned short* __restrict__ src, unsigned short* __restrict__ dst) {
    __shared__ unsigned short tile[128 * 68];
    int t = threadIdx.x;
    int l0 = blockIdx.x * 128, h = blockIdx.y, b = blockIdx.z;
#pragma unroll
    for (int i = 0; i < 8; i++) {
        int u = t + i * 256;                 // ushort4 units
        int l = u >> 4, c4 = (u & 15) * 4;
        u16x4 v4 = *(const u16x4*)&src[((size_t)(b * LL + l0 + l)) * DD + h * DK + c4];
        tile[l * 68 + c4 + 0] = v4[0]; tile[l * 68 + c4 + 1] = v4[1];
        tile[l * 68 + c4 + 2] = v4[2]; tile[l * 68 + c4 + 3] = v4[3];
    }
    __syncthreads();
    size_t ob = ((size_t)(b * HH + h)) * DK * LL;
#pragma unroll
    for (int i = 0; i < 8; i++) {
        int u = t + i * 256;                 // ushort4 units along l
        int d = u >> 5, lq = (u & 31) * 4;
        u16x4 o;
#pragma unroll
        for (int j = 0; j < 4; j++) o[j] = tile[(lq + j) * 68 + d];
        *(u16x4*)&dst[ob + (size_t)d * LL + l0 + lq] = o;
    }
}

// ---------------- alv = (A @ Wp + bias) transposed to (B,H,L) ----------------
__global__ __launch_bounds__(256)
void alv_gemm(const float* __restrict__ A, const float* __restrict__ Wp,
              const float* __restrict__ bias, float* __restrict__ alv) {
    __shared__ float As[16][65];
    __shared__ float Ws[64][17];
    int t = threadIdx.x;
    int m0 = blockIdx.x * 16;
    int r = t >> 4, hh = t & 15;
    float acc = 0.f;
    for (int kt = 0; kt < 16; kt++) {
        __syncthreads();
#pragma unroll
        for (int i = 0; i < 4; i++) {
            int e = t + i * 256;
            int rr = e >> 6, kk = e & 63;
            As[rr][kk] = A[(size_t)(m0 + rr) * DD + kt * 64 + kk];
        }
#pragma unroll
        for (int i = 0; i < 4; i++) {
            int e = t + i * 256;
            int kk = e >> 4, h2 = e & 15;
            Ws[kk][h2] = Wp[(size_t)(kt * 64 + kk) * HH + h2];
        }
        __syncthreads();
#pragma unroll
        for (int kk = 0; kk < 64; kk++) acc += As[r][kk] * Ws[kk][hh];
    }
    int m = m0 + r;
    int b = m >> 9, l = m & 511;
    alv[(size_t)(b * HH + hh) * LL + l] = acc + bias[hh];
}

// ---------------- clustering ----------------
__global__ __launch_bounds__(256)
void cluster_kernel(const float* __restrict__ zsrc, const float* __restrict__ alv,
                    const float* __restrict__ mu, const float* __restrict__ logvar,
                    const float* __restrict__ logprior,
                    float* __restrict__ cp_out, float* __restrict__ lpdf_out,
                    unsigned int* __restrict__ maxenc, float* __restrict__ kl_out,
                    int isHead) {
    __shared__ float s_mu[CC * DK], s_iv[CC * DK], s_lv[CC * DK];
    __shared__ float s_slv[CC], s_siv[CC], s_lp[CC];
    __shared__ float s_red[256];
    int t = threadIdx.x;
    int tile = blockIdx.x & 1;
    int bh = blockIdx.x >> 1;
    int h = bh & (HH - 1), b = bh >> 4;
    int hm = isHead ? 0 : h;

    {
        float m = mu[hm * CC * DK + t];
        float lv = logvar[hm * CC * DK + t];
        s_mu[t] = m; s_lv[t] = lv; s_iv[t] = expf(-lv);
    }
    __syncthreads();
    if (t < CC) {
        float slv = 0.f, siv = 0.f;
        for (int d = 0; d < DK; d++) { slv += s_lv[t * DK + d]; siv += s_iv[t * DK + d]; }
        s_slv[t] = slv; s_siv[t] = siv;
    }
    if (t == CC) {
        float x[CC];
        float m = -1e30f;
        for (int c = 0; c < CC; c++) { x[c] = logprior[hm * CC + c]; m = fmaxf(m, x[c]); }
        float se = 0.f;
        for (int c = 0; c < CC; c++) se += expf(x[c] - m);
        float lse = m + logf(se);
        for (int c = 0; c < CC; c++) s_lp[c] = x[c] - lse;
    }
    __syncthreads();

    int l = tile * 256 + t;
    const float* zp = zsrc + ((size_t)(b * LL + l)) * DD + h * DK;
    float acc[CC] = {0.f, 0.f, 0.f, 0.f};
    for (int d = 0; d < DK; d += 4) {
        float4 z4 = *(const float4*)(zp + d);
#pragma unroll
        for (int c = 0; c < CC; c++) {
            float d0 = z4.x - s_mu[c * DK + d];     acc[c] += d0 * d0 * s_iv[c * DK + d];
            float d1 = z4.y - s_mu[c * DK + d + 1]; acc[c] += d1 * d1 * s_iv[c * DK + d + 1];
            float d2 = z4.z - s_mu[c * DK + d + 2]; acc[c] += d2 * d2 * s_iv[c * DK + d + 2];
            float d3 = z4.w - s_mu[c * DK + d + 3]; acc[c] += d3 * d3 * s_iv[c * DK + d + 3];
        }
    }
    float lpdf[CC];
#pragma unroll
    for (int c = 0; c < CC; c++)
        lpdf[c] = -0.5f * acc[c] - 0.5f * s_slv[c] - NEG_DPI + s_lp[c];
    float m = fmaxf(fmaxf(lpdf[0], lpdf[1]), fmaxf(lpdf[2], lpdf[3]));
    float se = 0.f;
#pragma unroll
    for (int c = 0; c < CC; c++) se += expf(lpdf[c] - m);
    float lse = m + logf(se);
    float lprob[CC], cpv[CC];
    size_t idx = ((size_t)(bh * LL + l)) * CC;
#pragma unroll
    for (int c = 0; c < CC; c++) {
        lprob[c] = lpdf[c] - lse;
        cpv[c] = expf(lprob[c]);
        cp_out[idx + c] = cpv[c];
    }
    if (isHead) {
#pragma unroll
        for (int c = 0; c < CC; c++) lpdf_out[idx + c] = lpdf[c];
    }
    float alvv = alv[(size_t)bh * LL + l];
    float avar = expf(alvv);
    float t1 = 0.f, t2 = 0.f;
#pragma unroll
    for (int c = 0; c < CC; c++) {
        t1 += expf(s_lp[c]) * (s_lp[c] - lprob[c]);
        t2 += cpv[c] * (acc[c] + avar * s_siv[c] + s_slv[c]);
    }
    float klv = t1 + 0.5f * t2 - 0.5f * (float)DK * (1.0f + alvv);
    float tot = block_sum256(klv, s_red);
    if (t == 0) atomicAdd(kl_out + b, tot * (1.0f / (HH * LL)));
    if (isHead) {
        float mt = block_max256(m, s_red);
        if (t == 0) atomicMax(maxenc, fenc(mt));
    }
}

// ---------------- pair stats: div loss (+ head: diag log_softmax(aff)) ----------------
__global__ __launch_bounds__(256)
void pairstats_kernel(const float* __restrict__ cp, float* __restrict__ div_out,
                      float* __restrict__ mi_out, int isHead) {
    __shared__ float s_cp[LL * CC];
    __shared__ float s_red[256];
    int t = threadIdx.x;
    int bh = blockIdx.x;
    int b = bh >> 4;
    const float* base = cp + (size_t)bh * LL * CC;
#pragma unroll
    for (int i = 0; i < 8; i++) s_cp[t + i * 256] = base[t + i * 256];
    __syncthreads();
    float divacc = 0.f, diagacc = 0.f;
    for (int qi = 0; qi < 2; qi++) {
        int q = t + qi * 256;
        float c0 = s_cp[q * 4 + 0], c1 = s_cp[q * 4 + 1], c2 = s_cp[q * 4 + 2], c3 = s_cp[q * 4 + 3];
        float m = -1e30f, s = 0.f, selfdot = 0.f;
        for (int k = 0; k < LL; k++) {
            float dot = c0 * s_cp[k * 4 + 0] + c1 * s_cp[k * 4 + 1] + c2 * s_cp[k * 4 + 2] + c3 * s_cp[k * 4 + 3];
            float del = (k == q) ? 1.f : 0.f;
            float dd = dot - del;
            divacc += dd * dd * (del * 1.25f + (1.f - del) * 0.75f);
            if (isHead) {
                if (dot > m) { s = s * expf(m - dot) + 1.f; m = dot; }
                else         { s += expf(dot - m); }
                if (k == q) selfdot = dot;
            }
        }
        if (isHead) diagacc += selfdot - (m + logf(s));
    }
    float dtot = block_sum256(divacc, s_red);
    if (t == 0) atomicAdd(div_out + b, dtot * (1.0f / ((float)HH * LL * LL)));
    if (isHead) {
        float gtot = block_sum256(diagacc, s_red);
        if (t == 0) atomicAdd(mi_out + b, -gtot * (1.0f / (HH * LL)));
    }
}

// ---------------- attention v4: MFMA, one (b,h,16-row q-tile) per block ----------------
// Phase1: S = (Q Kt)/8 via 3-pass split-bf16 MFMA (frags direct from global/L2).
// Phase2: softmax+mask+renorm; normalized P written (plain coalesced float4) to
//         per-head scratch attn_h[b][hl][q][k] (hl = h - h0, 8 heads/pass).
// Phase3: ctx = P V via 3-pass MFMA against pre-transposed Vt.
__global__ __launch_bounds__(256)
void attn3_kernel(const unsigned short* __restrict__ qoh, const unsigned short* __restrict__ qol,
                  const unsigned short* __restrict__ koh, const unsigned short* __restrict__ kol,
                  const unsigned short* __restrict__ vth, const unsigned short* __restrict__ vtl,
                  const float* __restrict__ cpq,
                  float* __restrict__ ctxf, float* __restrict__ attn_h, int h0) {
    // union: S fp32 [16][516] (33024 B)  /  Ph,Pl bf16 [16][520] each (33280 B)
    __shared__ __align__(16) char sbuf[33280];
    __shared__ float s_cp[LL * CC];    // 8 KB
    __shared__ float s_inv[16];
    float* S = (float*)sbuf;
    unsigned short* Ph = (unsigned short*)sbuf;
    unsigned short* Pl = Ph + 16 * 520;

    int t = threadIdx.x;
    int qt = blockIdx.x, hl = blockIdx.y, b = blockIdx.z;
    int h = h0 + hl;
    int q0 = qt * 16;
    int lane = t & 63, w = t >> 6;
    int lm = lane & 15, quad = lane >> 4;
    int bh = b * HH + h;

    // stage cp rows for this (b,h)
    {
        const float* cpb = cpq + (size_t)bh * LL * CC;
#pragma unroll
        for (int i = 0; i < 2; i++) {
            int e = t + i * 256;                  // float4 unit
            *(float4*)&s_cp[e * 4] = *(const float4*)&cpb[e * 4];
        }
    }

    // ---- phase 1: scores ----
    size_t qbase = ((size_t)(b * LL + q0 + lm)) * DD + h * DK + quad * 8;
    short8 qah0 = *(const short8*)(qoh + qbase);
    short8 qah1 = *(const short8*)(qoh + qbase + 32);
    short8 qal0 = *(const short8*)(qol + qbase);
    short8 qal1 = *(const short8*)(qol + qbase + 32);

    floatx4 sa[8] = {};
#pragma unroll
    for (int j = 0; j < 8; j++) {
        int n0 = w * 128 + j * 16;
        size_t kbase = ((size_t)(b * LL + n0 + lm)) * DD + h * DK + quad * 8;
        short8 kbh0 = *(const short8*)(koh + kbase);
        short8 kbh1 = *(const short8*)(koh + kbase + 32);
        short8 kbl0 = *(const short8*)(kol + kbase);
        short8 kbl1 = *(const short8*)(kol + kbase + 32);
        sa[j] = __builtin_amdgcn_mfma_f32_16x16x32_bf16(qah0, kbh0, sa[j], 0, 0, 0);
        sa[j] = __builtin_amdgcn_mfma_f32_16x16x32_bf16(qah1, kbh1, sa[j], 0, 0, 0);
        sa[j] = __builtin_amdgcn_mfma_f32_16x16x32_bf16(qah0, kbl0, sa[j], 0, 0, 0);
        sa[j] = __builtin_amdgcn_mfma_f32_16x16x32_bf16(qah1, kbl1, sa[j], 0, 0, 0);
        sa[j] = __builtin_amdgcn_mfma_f32_16x16x32_bf16(qal0, kbh0, sa[j], 0, 0, 0);
        sa[j] = __builtin_amdgcn_mfma_f32_16x16x32_bf16(qal1, kbh1, sa[j], 0, 0, 0);
    }
    __syncthreads();   // s_cp staged; S buffer free
#pragma unroll
    for (int j = 0; j < 8; j++) {
        int kc = w * 128 + j * 16 + lm;
#pragma unroll
        for (int r = 0; r < 4; r++)
            S[(quad * 4 + r) * 516 + kc] = sa[j][r] * 0.125f;
    }
    __syncthreads();

    // ---- phase 2a: softmax + mask + renorm factor (16 lanes per row) ----
    {
        int r = t >> 4, ln = t & 15;
        float m = -1e30f;
        for (int k = ln; k < LL; k += 16) m = fmaxf(m, S[r * 516 + k]);
#pragma unroll
        for (int off = 8; off > 0; off >>= 1) m = fmaxf(m, __shfl_xor(m, off, 16));
        float4 cq = *(float4*)&s_cp[(q0 + r) * 4];
        float Z = 0.f, Sm = 0.f;
        for (int k = ln; k < LL; k += 16) {
            float e = expf(S[r * 516 + k] - m);
            float4 ck = *(float4*)&s_cp[k * 4];
            float mask = cq.x * ck.x + cq.y * ck.y + cq.z * ck.z + cq.w * ck.w;
            float a = e * mask;
            Z += e; Sm += a;
            S[r * 516 + k] = a;
        }
#pragma unroll
        for (int off = 8; off > 0; off >>= 1) {
            Z += __shfl_xor(Z, off, 16);
            Sm += __shfl_xor(Sm, off, 16);
        }
        if (ln == 0) s_inv[r] = 1.f / (Sm + 1e-6f * Z);
    }
    __syncthreads();

    // ---- phase 2b: normalize into regs + plain coalesced write of per-head P ----
    float4 pv[8];
#pragma unroll
    for (int i = 0; i < 8; i++) {
        int e = t + i * 256;                 // float4 unit, 2048 total
        int r2 = e >> 7, k4 = (e & 127) * 4;
        float4 p = *(float4*)&S[r2 * 516 + k4];
        float inv = s_inv[r2];
        p.x *= inv; p.y *= inv; p.z *= inv; p.w *= inv;
        pv[i] = p;
        *(float4*)&attn_h[(((size_t)((b * 8 + hl) * LL + q0 + r2)) * LL) + k4] = p;
    }
    __syncthreads();   // all reads of S done; overwrite with Ph/Pl
#pragma unroll
    for (int i = 0; i < 8; i++) {
        int e = t + i * 256;
        int r2 = e >> 7, k4 = (e & 127) * 4;
        float c[4] = {pv[i].x, pv[i].y, pv[i].z, pv[i].w};
        u16x4 hv, lv;
#pragma unroll
        for (int j = 0; j < 4; j++) {
            unsigned short hb = f2bf(c[j]);
            hv[j] = hb;
            lv[j] = f2bf(c[j] - bf2f(hb));
        }
        *(u16x4*)&Ph[r2 * 520 + k4] = hv;
        *(u16x4*)&Pl[r2 * 520 + k4] = lv;
    }
    __syncthreads();

    // ---- phase 3: ctx = P @ V via Vt ----
    int dn = w * 16 + lm;
    const unsigned short* vrh = vth + ((size_t)bh * DK + dn) * LL;
    const unsigned short* vrl = vtl + ((size_t)bh * DK + dn) * LL;
    floatx4 ca = {};
#pragma unroll
    for (int kc = 0; kc < 16; kc++) {
        int kb = kc * 32 + quad * 8;
        short8 pah = *(const short8*)&Ph[lm * 520 + kb];
        short8 pal = *(const short8*)&Pl[lm * 520 + kb];
        short8 vbh = *(const short8*)(vrh + kb);
        short8 vbl = *(const short8*)(vrl + kb);
        ca = __builtin_amdgcn_mfma_f32_16x16x32_bf16(pah, vbh, ca, 0, 0, 0);
        ca = __builtin_amdgcn_mfma_f32_16x16x32_bf16(pah, vbl, ca, 0, 0, 0);
        ca = __builtin_amdgcn_mfma_f32_16x16x32_bf16(pal, vbh, ca, 0, 0, 0);
    }
#pragma unroll
    for (int r = 0; r < 4; r++)
        ctxf[((size_t)(b * LL + q0 + quad * 4 + r)) * DD + h * DK + dn] = ca[r];
}

// ---------------- reduce per-head probs into attn mean (8 heads per pass) ----------------
__global__ __launch_bounds__(256)
void attn_reduce(const float* __restrict__ attn_h, float* __restrict__ attn_out,
                 int accumulate) {
    int e = blockIdx.x * 256 + threadIdx.x;  // float4 unit; total B*L*L/4
    int b = e >> 16;
    int rem = e & 65535;
    float4 s = {0.f, 0.f, 0.f, 0.f};
#pragma unroll
    for (int hl = 0; hl < 8; hl++) {
        float4 v = ((const float4*)attn_h)[(((size_t)(b * 8 + hl)) << 16) + rem];
        s.x += v.x; s.y += v.y; s.z += v.z; s.w += v.w;
    }
    float4* o = (float4*)attn_out + (((size_t)b) << 16) + rem;
    const float sc = 1.0f / (float)HH;
    float4 prev = {0.f, 0.f, 0.f, 0.f};
    if (accumulate) prev = *o;
    prev.x += s.x * sc; prev.y += s.y * sc; prev.z += s.z * sc; prev.w += s.w * sc;
    *o = prev;
}

// ---------------- MI: pdf + wsum ----------------
__global__ __launch_bounds__(256)
void wsum_kernel(const float* __restrict__ lpdf, const float* __restrict__ cp,
                 const unsigned int* __restrict__ maxenc,
                 float* __restrict__ pdf_out, float* __restrict__ wsum_out) {
    __shared__ float s_red[256];
    int t = threadIdx.x;
    int bh = blockIdx.x;
    float M = fdec(*maxenc);
    float a[CC] = {0.f, 0.f, 0.f, 0.f};
    for (int li = 0; li < 2; li++) {
        int l = t + li * 256;
        size_t idx = ((size_t)bh * LL + l) * CC;
        float p0 = expf(lpdf[idx + 0] - M);
        float p1 = expf(lpdf[idx + 1] - M);
        float p2 = expf(lpdf[idx + 2] - M);
        float p3 = expf(lpdf[idx + 3] - M);
        float pd = p0 + p1 + p2 + p3;
        pdf_out[(size_t)bh * LL + l] = pd;
        a[0] += cp[idx + 0] * pd; a[1] += cp[idx + 1] * pd;
        a[2] += cp[idx + 2] * pd; a[3] += cp[idx + 3] * pd;
    }
#pragma unroll
    for (int c = 0; c < CC; c++) {
        float tot = block_sum256(a[c], s_red);
        if (t == 0) wsum_out[bh * CC + c] = tot;
    }
}

// ---------------- MI: pairwise head overlap ----------------
__global__ __launch_bounds__(256)
void mi_kernel(const float* __restrict__ cp, const float* __restrict__ pdf,
               const float* __restrict__ wsum, float* __restrict__ mi_out) {
    __shared__ float s_q[HH * CC];
    __shared__ float s_c[HH * CC];
    __shared__ float s_red[256];
    int t = threadIdx.x;
    int b = blockIdx.x >> 9;
    int l = blockIdx.x & 511;
    if (t < HH * CC) {
        int i = t >> 2, c = t & 3;
        float cpv = cp[((size_t)(b * HH + i) * LL + l) * CC + c];
        s_c[t] = cpv;
        float w = cpv * pdf[(size_t)(b * HH + i) * LL + l];
        float ws = wsum[(b * HH + i) * CC + c];
        s_q[t] = w / fmaxf(ws, 1e-6f);
    }
    __syncthreads();
    int i = t >> 4, j = t & 15;
    float sdot = 0.f;
#pragma unroll
    for (int c = 0; c < CC; c++) sdot += s_q[i * 4 + c] * s_c[j * 4 + c];
    float mi_p = fminf(sdot, 1.f);
    float val = (i != j) ? logf(1.f - mi_p + 1e-6f) : 0.f;
    float tot = block_sum256(val, s_red);
    if (t == 0) atomicAdd(mi_out + b, -10.f * tot * (1.0f / ((float)LL * HH * HH)));
}

// ---------------- launcher ----------------
extern "C" void kernel_launch(void* const* d_in, const int* in_sizes, int n_in,
                              void* d_out, int out_size, void* d_ws, size_t ws_size,
                              hipStream_t stream) {
    (void)in_sizes; (void)n_in; (void)out_size; (void)ws_size;
    const float* query  = (const float*)d_in[0];
    const float* key    = (const float*)d_in[1];
    const float* value  = (const float*)d_in[2];
    const float* Wq     = (const float*)d_in[3];
    const float* bq     = (const float*)d_in[4];
    const float* Wk     = (const float*)d_in[5];
    const float* bk     = (const float*)d_in[6];
    const float* Wv     = (const float*)d_in[7];
    const float* bv     = (const float*)d_in[8];
    const float* Wo     = (const float*)d_in[9];
    const float* bo     = (const float*)d_in[10];
    const float* Wsem   = (const float*)d_in[11];
    const float* bsem   = (const float*)d_in[12];
    const float* Whead  = (const float*)d_in[13];
    const float* bhead  = (const float*)d_in[14];
    const float* tokmu  = (const float*)d_in[15];
    const float* toklv  = (const float*)d_in[16];
    const float* toklp  = (const float*)d_in[17];
    const float* headmu = (const float*)d_in[18];
    const float* headlv = (const float*)d_in[19];
    const float* headlp = (const float*)d_in[20];

    float* ws   = (float*)d_ws;
    const size_t NBLD = (size_t)BB * LL * DD;      // 4194304
    float* q    = ws;                               // fp32 q (cluster/alv need it)
    float* ctxf = ws + NBLD;
    float* alvq = ws + 2 * NBLD;
    float* alvh = alvq + (size_t)BB * HH * LL;
    float* cpq  = alvh + (size_t)BB * HH * LL;
    float* cph  = cpq + (size_t)BB * HH * LL * CC;
    float* lpdfh= cph + (size_t)BB * HH * LL * CC;
    float* pdfb = lpdfh + (size_t)BB * HH * LL * CC;
    float* wsumb= pdfb + (size_t)BB * HH * LL;
    unsigned int* maxenc = (unsigned int*)(wsumb + (size_t)BB * HH * CC);
    float* attn_h = (float*)(maxenc + 4);           // 8 heads x B x L x L fp32 = 67 MB

    // bf16 scratch (ushort)
    unsigned short* us = (unsigned short*)(attn_h + (size_t)BB * 8 * LL * LL);
    const size_t WSZ = (size_t)DD * DD;            // 1048576
    unsigned short* ist_h = us;                    // input staging (reused serially)
    unsigned short* ist_l = ist_h + NBLD;
    unsigned short* qoh = ist_l + NBLD;
    unsigned short* qol = qoh + NBLD;
    unsigned short* koh = qol + NBLD;
    unsigned short* kol = koh + NBLD;
    unsigned short* voh = kol + NBLD;
    unsigned short* vol = voh + NBLD;
    unsigned short* vth = vol + NBLD;              // Vt[d][l] per (b,h)
    unsigned short* vtl = vth + NBLD;
    unsigned short* wqh = vtl + NBLD;
    unsigned short* wql = wqh + WSZ;
    unsigned short* wkh = wql + WSZ;
    unsigned short* wkl = wkh + WSZ;
    unsigned short* wvh = wkl + WSZ;
    unsigned short* wvl = wvh + WSZ;
    unsigned short* woh = wvl + WSZ;
    unsigned short* wol = woh + WSZ;

    float* out      = (float*)d_out;
    float* attn_out = out + NBLD;
    float* kl_out   = attn_out + (size_t)BB * LL * LL;
    float* div_out  = kl_out + BB;
    float* mi_out   = div_out + BB;

    hipMemsetAsync(kl_out, 0, 3 * BB * sizeof(float), stream);
    hipMemsetAsync(maxenc, 0, sizeof(unsigned int), stream);

    dim3 wg(16, 16);
    wconv_kernel<<<wg, 256, 0, stream>>>(Wq, wqh, wql);
    wconv_kernel<<<wg, 256, 0, stream>>>(Wk, wkh, wkl);
    wconv_kernel<<<wg, 256, 0, stream>>>(Wv, wvh, wvl);
    wconv_kernel<<<wg, 256, 0, stream>>>(Wo, woh, wol);

    dim3 gg(DD / 128, BB * LL / 128);  // (8, 32)
    convert_hilo<<<NBLD / 1024, 256, 0, stream>>>(query, ist_h, ist_l);
    mfma_gemm_bias<<<gg, 256, 0, stream>>>(ist_h, ist_l, wqh, wql, bq, q, qoh, qol);
    convert_hilo<<<NBLD / 1024, 256, 0, stream>>>(key, ist_h, ist_l);
    mfma_gemm_bias<<<gg, 256, 0, stream>>>(ist_h, ist_l, wkh, wkl, bk, nullptr, koh, kol);
    convert_hilo<<<NBLD / 1024, 256, 0, stream>>>(value, ist_h, ist_l);
    mfma_gemm_bias<<<gg, 256, 0, stream>>>(ist_h, ist_l, wvh, wvl, bv, nullptr, voh, vol);

    dim3 vtg(LL / 128, HH, BB);
    vt_prep<<<vtg, 256, 0, stream>>>(voh, vth);
    vt_prep<<<vtg, 256, 0, stream>>>(vol, vtl);

    alv_gemm<<<BB * LL / 16, 256, 0, stream>>>(q, Wsem, bsem, alvq);
    cluster_kernel<<<BB * HH * 2, 256, 0, stream>>>(q, alvq, tokmu, toklv, toklp,
                                                    cpq, nullptr, nullptr, kl_out, 0);
    pairstats_kernel<<<BB * HH, 256, 0, stream>>>(cpq, div_out, nullptr, 0);

    for (int h0 = 0; h0 < HH; h0 += 8) {
        attn3_kernel<<<dim3(LL / 16, 8, BB), 256, 0, stream>>>(
            qoh, qol, koh, kol, vth, vtl, cpq, ctxf, attn_h, h0);
        attn_reduce<<<BB * LL * LL / 4 / 256, 256, 0, stream>>>(
            attn_h, attn_out, h0 > 0 ? 1 : 0);
    }

    convert_hilo<<<NBLD / 1024, 256, 0, stream>>>(ctxf, ist_h, ist_l);
    alv_gemm<<<BB * LL / 16, 256, 0, stream>>>(ctxf, Whead, bhead, alvh);
    cluster_kernel<<<BB * HH * 2, 256, 0, stream>>>(ctxf, alvh, headmu, headlv, headlp,
                                                    cph, lpdfh, maxenc, kl_out, 1);
    pairstats_kernel<<<BB * HH, 256, 0, stream>>>(cph, div_out, mi_out, 1);
    wsum_kernel<<<BB * HH, 256, 0, stream>>>(lpdfh, cph, maxenc, pdfb, wsumb);
    mi_kernel<<<BB * LL, 256, 0, stream>>>(cph, pdfb, wsumb, mi_out);
    mfma_gemm_bias<<<gg, 256, 0, stream>>>(ist_h, ist_l, woh, wol, bo, out, nullptr, nullptr);
}

// Round 6
// 843.091 us; speedup vs baseline: 1.5356x; 1.1622x over previous
//
#include <hip/hip_runtime.h>
#include <math.h>

// Problem constants: B=8, L=512, D=1024, H=16, C=4, Dk=64
#define BB 8
#define LL 512
#define DD 1024
#define HH 16
#define CC 4
#define DK 64
#define NEG_DPI 201.06192982974676f   // 64 * pi

typedef __attribute__((ext_vector_type(8))) short short8;     // MFMA A/B frag (8 bf16)
typedef __attribute__((ext_vector_type(4))) float floatx4;    // MFMA C/D frag
typedef __attribute__((ext_vector_type(8))) unsigned short u16x8;
typedef __attribute__((ext_vector_type(4))) unsigned short u16x4;

// ---------------- helpers ----------------
__device__ inline float block_sum256(float v, float* s_red) {
    int t = threadIdx.x;
    s_red[t] = v; __syncthreads();
    for (int off = 128; off > 0; off >>= 1) {
        if (t < off) s_red[t] += s_red[t + off];
        __syncthreads();
    }
    float r = s_red[0]; __syncthreads();
    return r;
}
__device__ inline float block_max256(float v, float* s_red) {
    int t = threadIdx.x;
    s_red[t] = v; __syncthreads();
    for (int off = 128; off > 0; off >>= 1) {
        if (t < off) s_red[t] = fmaxf(s_red[t], s_red[t + off]);
        __syncthreads();
    }
    float r = s_red[0]; __syncthreads();
    return r;
}
__device__ inline unsigned int fenc(float f) {
    unsigned int b = __float_as_uint(f);
    return (b & 0x80000000u) ? ~b : (b | 0x80000000u);
}
__device__ inline float fdec(unsigned int u) {
    return (u & 0x80000000u) ? __uint_as_float(u ^ 0x80000000u) : __uint_as_float(~u);
}
__device__ inline unsigned short f2bf(float x) {   // RNE fp32 -> bf16
    unsigned int u = __float_as_uint(x);
    return (unsigned short)((u + 0x7FFFu + ((u >> 16) & 1u)) >> 16);
}
__device__ inline float bf2f(unsigned short h) {
    return __uint_as_float((unsigned int)h << 16);
}

// ---------------- fp32 -> bf16 hi/lo split (elementwise) ----------------
__global__ __launch_bounds__(256)
void convert_hilo(const float* __restrict__ x, unsigned short* __restrict__ hh,
                  unsigned short* __restrict__ ll) {
    int i = blockIdx.x * 256 + threadIdx.x;     // float4 unit
    float4 v = ((const float4*)x)[i];
    u16x4 h, l;
    float c[4] = {v.x, v.y, v.z, v.w};
#pragma unroll
    for (int j = 0; j < 4; j++) {
        unsigned short hb = f2bf(c[j]);
        h[j] = hb;
        l[j] = f2bf(c[j] - bf2f(hb));
    }
    ((u16x4*)hh)[i] = h;
    ((u16x4*)ll)[i] = l;
}

// ---------------- weight transpose + hi/lo convert: W[K][N] -> Wt[N][K] ----------------
__global__ __launch_bounds__(256)
void wconv_kernel(const float* __restrict__ W, unsigned short* __restrict__ Th,
                  unsigned short* __restrict__ Tl) {
    __shared__ float tile[64][65];
    int t = threadIdx.x;
    int n0 = blockIdx.x * 64, k0 = blockIdx.y * 64;
    int r = t >> 4, c4 = (t & 15) * 4;
#pragma unroll
    for (int rr = 0; rr < 64; rr += 16) {
        float4 v = *(const float4*)&W[(size_t)(k0 + r + rr) * DD + n0 + c4];
        tile[r + rr][c4 + 0] = v.x; tile[r + rr][c4 + 1] = v.y;
        tile[r + rr][c4 + 2] = v.z; tile[r + rr][c4 + 3] = v.w;
    }
    __syncthreads();
    int rn = t >> 2, kg = (t & 3) * 16;
    u16x8 oh[2], ol[2];
#pragma unroll
    for (int j = 0; j < 16; j++) {
        float x = tile[kg + j][rn];
        unsigned short hb = f2bf(x);
        oh[j >> 3][j & 7] = hb;
        ol[j >> 3][j & 7] = f2bf(x - bf2f(hb));
    }
    size_t o = (size_t)(n0 + rn) * DD + k0 + kg;
    *(u16x8*)&Th[o] = oh[0]; *(u16x8*)&Th[o + 8] = oh[1];
    *(u16x8*)&Tl[o] = ol[0]; *(u16x8*)&Tl[o + 8] = ol[1];
}

// ---------------- split-bf16 MFMA GEMM: C = A @ Wt^T + bias; fp32 and/or hi-lo out ----------------
__global__ __launch_bounds__(256)
void mfma_gemm_bias(const unsigned short* __restrict__ Ah, const unsigned short* __restrict__ Al,
                    const unsigned short* __restrict__ Bh, const unsigned short* __restrict__ Bl,
                    const float* __restrict__ bias, float* __restrict__ C,
                    unsigned short* __restrict__ Ch, unsigned short* __restrict__ Cl) {
    __shared__ unsigned short sAh[128 * 32];
    __shared__ unsigned short sAl[128 * 32];
    __shared__ unsigned short sBh[128 * 32];
    __shared__ unsigned short sBl[128 * 32];
    int t = threadIdx.x;
    int n0 = blockIdx.x * 128, m0 = blockIdx.y * 128;
    int lane = t & 63, w = t >> 6;
    int wm = w >> 1, wn = w & 1;
    int lm = lane & 15, quad = lane >> 4;
    int srow = t >> 1, sk = (t & 1) * 16;

    const unsigned short* gAh = Ah + (size_t)(m0 + srow) * DD + sk;
    const unsigned short* gAl = Al + (size_t)(m0 + srow) * DD + sk;
    const unsigned short* gBh = Bh + (size_t)(n0 + srow) * DD + sk;
    const unsigned short* gBl = Bl + (size_t)(n0 + srow) * DD + sk;
    unsigned short* wAh = &sAh[srow * 32 + sk];
    unsigned short* wAl = &sAl[srow * 32 + sk];
    unsigned short* wBh = &sBh[srow * 32 + sk];
    unsigned short* wBl = &sBl[srow * 32 + sk];

    floatx4 acc[4][4] = {};

    for (int kt = 0; kt < 32; kt++) {
        int kb = kt * 32;
        u16x8 a0 = *(const u16x8*)(gAh + kb);
        u16x8 a1 = *(const u16x8*)(gAh + kb + 8);
        u16x8 a2 = *(const u16x8*)(gAl + kb);
        u16x8 a3 = *(const u16x8*)(gAl + kb + 8);
        u16x8 b0 = *(const u16x8*)(gBh + kb);
        u16x8 b1 = *(const u16x8*)(gBh + kb + 8);
        u16x8 b2 = *(const u16x8*)(gBl + kb);
        u16x8 b3 = *(const u16x8*)(gBl + kb + 8);
        __syncthreads();
        *(u16x8*)(wAh) = a0; *(u16x8*)(wAh + 8) = a1;
        *(u16x8*)(wAl) = a2; *(u16x8*)(wAl + 8) = a3;
        *(u16x8*)(wBh) = b0; *(u16x8*)(wBh + 8) = b1;
        *(u16x8*)(wBl) = b2; *(u16x8*)(wBl + 8) = b3;
        __syncthreads();

        short8 bh[4], bl[4];
#pragma unroll
        for (int j = 0; j < 4; j++) {
            int nb = (wn * 64 + j * 16 + lm) * 32 + quad * 8;
            bh[j] = *(const short8*)&sBh[nb];
            bl[j] = *(const short8*)&sBl[nb];
        }
#pragma unroll
        for (int i = 0; i < 4; i++) {
            int ab = (wm * 64 + i * 16 + lm) * 32 + quad * 8;
            short8 ah = *(const short8*)&sAh[ab];
            short8 al = *(const short8*)&sAl[ab];
#pragma unroll
            for (int j = 0; j < 4; j++) {
                acc[i][j] = __builtin_amdgcn_mfma_f32_16x16x32_bf16(ah, bh[j], acc[i][j], 0, 0, 0);
                acc[i][j] = __builtin_amdgcn_mfma_f32_16x16x32_bf16(ah, bl[j], acc[i][j], 0, 0, 0);
                acc[i][j] = __builtin_amdgcn_mfma_f32_16x16x32_bf16(al, bh[j], acc[i][j], 0, 0, 0);
            }
        }
    }
#pragma unroll
    for (int i = 0; i < 4; i++) {
#pragma unroll
        for (int j = 0; j < 4; j++) {
            int n = n0 + wn * 64 + j * 16 + lm;
            float bv = bias[n];
#pragma unroll
            for (int r = 0; r < 4; r++) {
                int m = m0 + wm * 64 + i * 16 + quad * 4 + r;
                size_t idx = (size_t)m * DD + n;
                float val = acc[i][j][r] + bv;
                if (C) C[idx] = val;
                if (Ch) {
                    unsigned short hb = f2bf(val);
                    Ch[idx] = hb;
                    Cl[idx] = f2bf(val - bf2f(hb));
                }
            }
        }
    }
}

// ---------------- V transpose to Vt[d][l] (bf16, one of hi/lo per call) ----------------
__global__ __launch_bounds__(256)
void vt_prep(const unsigned short* __restrict__ src, unsigned short* __restrict__ dst) {
    __shared__ unsigned short tile[128 * 68];
    int t = threadIdx.x;
    int l0 = blockIdx.x * 128, h = blockIdx.y, b = blockIdx.z;
#pragma unroll
    for (int i = 0; i < 8; i++) {
        int u = t + i * 256;                 // ushort4 units
        int l = u >> 4, c4 = (u & 15) * 4;
        u16x4 v4 = *(const u16x4*)&src[((size_t)(b * LL + l0 + l)) * DD + h * DK + c4];
        tile[l * 68 + c4 + 0] = v4[0]; tile[l * 68 + c4 + 1] = v4[1];
        tile[l * 68 + c4 + 2] = v4[2]; tile[l * 68 + c4 + 3] = v4[3];
    }
    __syncthreads();
    size_t ob = ((size_t)(b * HH + h)) * DK * LL;
#pragma unroll
    for (int i = 0; i < 8; i++) {
        int u = t + i * 256;                 // ushort4 units along l
        int d = u >> 5, lq = (u & 31) * 4;
        u16x4 o;
#pragma unroll
        for (int j = 0; j < 4; j++) o[j] = tile[(lq + j) * 68 + d];
        *(u16x4*)&dst[ob + (size_t)d * LL + l0 + lq] = o;
    }
}

// ---------------- alv = (A @ Wp + bias) transposed to (B,H,L) ----------------
__global__ __launch_bounds__(256)
void alv_gemm(const float* __restrict__ A, const float* __restrict__ Wp,
              const float* __restrict__ bias, float* __restrict__ alv) {
    __shared__ float As[16][65];
    __shared__ float Ws[64][17];
    int t = threadIdx.x;
    int m0 = blockIdx.x * 16;
    int r = t >> 4, hh = t & 15;
    float acc = 0.f;
    for (int kt = 0; kt < 16; kt++) {
        __syncthreads();
#pragma unroll
        for (int i = 0; i < 4; i++) {
            int e = t + i * 256;
            int rr = e >> 6, kk = e & 63;
            As[rr][kk] = A[(size_t)(m0 + rr) * DD + kt * 64 + kk];
        }
#pragma unroll
        for (int i = 0; i < 4; i++) {
            int e = t + i * 256;
            int kk = e >> 4, h2 = e & 15;
            Ws[kk][h2] = Wp[(size_t)(kt * 64 + kk) * HH + h2];
        }
        __syncthreads();
#pragma unroll
        for (int kk = 0; kk < 64; kk++) acc += As[r][kk] * Ws[kk][hh];
    }
    int m = m0 + r;
    int b = m >> 9, l = m & 511;
    alv[(size_t)(b * HH + hh) * LL + l] = acc + bias[hh];
}

// ---------------- clustering ----------------
__global__ __launch_bounds__(256)
void cluster_kernel(const float* __restrict__ zsrc, const float* __restrict__ alv,
                    const float* __restrict__ mu, const float* __restrict__ logvar,
                    const float* __restrict__ logprior,
                    float* __restrict__ cp_out, float* __restrict__ lpdf_out,
                    unsigned int* __restrict__ maxenc, float* __restrict__ kl_out,
                    int isHead) {
    __shared__ float s_mu[CC * DK], s_iv[CC * DK], s_lv[CC * DK];
    __shared__ float s_slv[CC], s_siv[CC], s_lp[CC];
    __shared__ float s_red[256];
    int t = threadIdx.x;
    int tile = blockIdx.x & 1;
    int bh = blockIdx.x >> 1;
    int h = bh & (HH - 1), b = bh >> 4;
    int hm = isHead ? 0 : h;

    {
        float m = mu[hm * CC * DK + t];
        float lv = logvar[hm * CC * DK + t];
        s_mu[t] = m; s_lv[t] = lv; s_iv[t] = expf(-lv);
    }
    __syncthreads();
    if (t < CC) {
        float slv = 0.f, siv = 0.f;
        for (int d = 0; d < DK; d++) { slv += s_lv[t * DK + d]; siv += s_iv[t * DK + d]; }
        s_slv[t] = slv; s_siv[t] = siv;
    }
    if (t == CC) {
        float x[CC];
        float m = -1e30f;
        for (int c = 0; c < CC; c++) { x[c] = logprior[hm * CC + c]; m = fmaxf(m, x[c]); }
        float se = 0.f;
        for (int c = 0; c < CC; c++) se += expf(x[c] - m);
        float lse = m + logf(se);
        for (int c = 0; c < CC; c++) s_lp[c] = x[c] - lse;
    }
    __syncthreads();

    int l = tile * 256 + t;
    const float* zp = zsrc + ((size_t)(b * LL + l)) * DD + h * DK;
    float acc[CC] = {0.f, 0.f, 0.f, 0.f};
    for (int d = 0; d < DK; d += 4) {
        float4 z4 = *(const float4*)(zp + d);
#pragma unroll
        for (int c = 0; c < CC; c++) {
            float d0 = z4.x - s_mu[c * DK + d];     acc[c] += d0 * d0 * s_iv[c * DK + d];
            float d1 = z4.y - s_mu[c * DK + d + 1]; acc[c] += d1 * d1 * s_iv[c * DK + d + 1];
            float d2 = z4.z - s_mu[c * DK + d + 2]; acc[c] += d2 * d2 * s_iv[c * DK + d + 2];
            float d3 = z4.w - s_mu[c * DK + d + 3]; acc[c] += d3 * d3 * s_iv[c * DK + d + 3];
        }
    }
    float lpdf[CC];
#pragma unroll
    for (int c = 0; c < CC; c++)
        lpdf[c] = -0.5f * acc[c] - 0.5f * s_slv[c] - NEG_DPI + s_lp[c];
    float m = fmaxf(fmaxf(lpdf[0], lpdf[1]), fmaxf(lpdf[2], lpdf[3]));
    float se = 0.f;
#pragma unroll
    for (int c = 0; c < CC; c++) se += expf(lpdf[c] - m);
    float lse = m + logf(se);
    float lprob[CC], cpv[CC];
    size_t idx = ((size_t)(bh * LL + l)) * CC;
#pragma unroll
    for (int c = 0; c < CC; c++) {
        lprob[c] = lpdf[c] - lse;
        cpv[c] = expf(lprob[c]);
        cp_out[idx + c] = cpv[c];
    }
    if (isHead) {
#pragma unroll
        for (int c = 0; c < CC; c++) lpdf_out[idx + c] = lpdf[c];
    }
    float alvv = alv[(size_t)bh * LL + l];
    float avar = expf(alvv);
    float t1 = 0.f, t2 = 0.f;
#pragma unroll
    for (int c = 0; c < CC; c++) {
        t1 += expf(s_lp[c]) * (s_lp[c] - lprob[c]);
        t2 += cpv[c] * (acc[c] + avar * s_siv[c] + s_slv[c]);
    }
    float klv = t1 + 0.5f * t2 - 0.5f * (float)DK * (1.0f + alvv);
    float tot = block_sum256(klv, s_red);
    if (t == 0) atomicAdd(kl_out + b, tot * (1.0f / (HH * LL)));
    if (isHead) {
        float mt = block_max256(m, s_red);
        if (t == 0) atomicMax(maxenc, fenc(mt));
    }
}

// ---------------- pair stats v2: div loss (+ head: diag log_softmax(aff)) ----------------
// grid: BH * 8 blocks; block handles 64 q rows of one (b,h); 4 threads per row,
// each covering k strided by 4. Row results combine via shfl_xor(1,2); online-LSE
// (m,s) pairs merge exactly. divacc/diag block-reduced, one atomicAdd per block.
__global__ __launch_bounds__(256)
void pairstats_kernel(const float* __restrict__ cp, float* __restrict__ div_out,
                      float* __restrict__ mi_out, int isHead) {
    __shared__ float s_cp[LL * CC];
    __shared__ float s_red[256];
    int t = threadIdx.x;
    int bh = blockIdx.x >> 3;
    int seg = blockIdx.x & 7;
    int b = bh >> 4;
    const float* base = cp + (size_t)bh * LL * CC;
#pragma unroll
    for (int i = 0; i < 2; i++) {
        int e = t + i * 256;               // float4 unit, 512 total
        *(float4*)&s_cp[e * 4] = *(const float4*)&base[e * 4];
    }
    __syncthreads();

    int q = seg * 64 + (t >> 2);
    int ln = t & 3;
    float4 cq = *(float4*)&s_cp[q * 4];
    float divacc = 0.f, m = -1e30f, s = 0.f, selfdot = 0.f;
    for (int k = ln; k < LL; k += 4) {
        float4 ck = *(float4*)&s_cp[k * 4];
        float dot = cq.x * ck.x + cq.y * ck.y + cq.z * ck.z + cq.w * ck.w;
        float del = (k == q) ? 1.f : 0.f;
        float dd = dot - del;
        divacc += dd * dd * (0.75f + 0.5f * del);
        if (isHead) {
            if (dot > m) { s = s * expf(m - dot) + 1.f; m = dot; }
            else         { s += expf(dot - m); }
            if (k == q) selfdot = dot;
        }
    }
    // combine 4 lanes of this row (same wave: lanes t, t^1, t^2, t^3)
#pragma unroll
    for (int off = 1; off <= 2; off <<= 1) divacc += __shfl_xor(divacc, off, 64);
    float diag = 0.f;
    if (isHead) {
#pragma unroll
        for (int off = 1; off <= 2; off <<= 1) {
            float om = __shfl_xor(m, off, 64);
            float os = __shfl_xor(s, off, 64);
            float nm = fmaxf(m, om);
            s = s * expf(m - nm) + os * expf(om - nm);
            m = nm;
        }
#pragma unroll
        for (int off = 1; off <= 2; off <<= 1) selfdot += __shfl_xor(selfdot, off, 64);
        diag = selfdot - (m + logf(s));
    }
    float dtot = block_sum256(ln == 0 ? divacc : 0.f, s_red);
    if (t == 0) atomicAdd(div_out + b, dtot * (1.0f / ((float)HH * LL * LL)));
    if (isHead) {
        float gtot = block_sum256(ln == 0 ? diag : 0.f, s_red);
        if (t == 0) atomicAdd(mi_out + b, -gtot * (1.0f / (HH * LL)));
    }
}

// ---------------- attention v4: MFMA, one (b,h,16-row q-tile) per block ----------------
__global__ __launch_bounds__(256)
void attn3_kernel(const unsigned short* __restrict__ qoh, const unsigned short* __restrict__ qol,
                  const unsigned short* __restrict__ koh, const unsigned short* __restrict__ kol,
                  const unsigned short* __restrict__ vth, const unsigned short* __restrict__ vtl,
                  const float* __restrict__ cpq,
                  float* __restrict__ ctxf, float* __restrict__ attn_h, int h0) {
    // union: S fp32 [16][516] (33024 B)  /  Ph,Pl bf16 [16][520] each (33280 B)
    __shared__ __align__(16) char sbuf[33280];
    __shared__ float s_cp[LL * CC];    // 8 KB
    __shared__ float s_inv[16];
    float* S = (float*)sbuf;
    unsigned short* Ph = (unsigned short*)sbuf;
    unsigned short* Pl = Ph + 16 * 520;

    int t = threadIdx.x;
    int qt = blockIdx.x, hl = blockIdx.y, b = blockIdx.z;
    int h = h0 + hl;
    int q0 = qt * 16;
    int lane = t & 63, w = t >> 6;
    int lm = lane & 15, quad = lane >> 4;
    int bh = b * HH + h;

    // stage cp rows for this (b,h)
    {
        const float* cpb = cpq + (size_t)bh * LL * CC;
#pragma unroll
        for (int i = 0; i < 2; i++) {
            int e = t + i * 256;                  // float4 unit
            *(float4*)&s_cp[e * 4] = *(const float4*)&cpb[e * 4];
        }
    }

    // ---- phase 1: scores ----
    size_t qbase = ((size_t)(b * LL + q0 + lm)) * DD + h * DK + quad * 8;
    short8 qah0 = *(const short8*)(qoh + qbase);
    short8 qah1 = *(const short8*)(qoh + qbase + 32);
    short8 qal0 = *(const short8*)(qol + qbase);
    short8 qal1 = *(const short8*)(qol + qbase + 32);

    floatx4 sa[8] = {};
#pragma unroll
    for (int j = 0; j < 8; j++) {
        int n0 = w * 128 + j * 16;
        size_t kbase = ((size_t)(b * LL + n0 + lm)) * DD + h * DK + quad * 8;
        short8 kbh0 = *(const short8*)(koh + kbase);
        short8 kbh1 = *(const short8*)(koh + kbase + 32);
        short8 kbl0 = *(const short8*)(kol + kbase);
        short8 kbl1 = *(const short8*)(kol + kbase + 32);
        sa[j] = __builtin_amdgcn_mfma_f32_16x16x32_bf16(qah0, kbh0, sa[j], 0, 0, 0);
        sa[j] = __builtin_amdgcn_mfma_f32_16x16x32_bf16(qah1, kbh1, sa[j], 0, 0, 0);
        sa[j] = __builtin_amdgcn_mfma_f32_16x16x32_bf16(qah0, kbl0, sa[j], 0, 0, 0);
        sa[j] = __builtin_amdgcn_mfma_f32_16x16x32_bf16(qah1, kbl1, sa[j], 0, 0, 0);
        sa[j] = __builtin_amdgcn_mfma_f32_16x16x32_bf16(qal0, kbh0, sa[j], 0, 0, 0);
        sa[j] = __builtin_amdgcn_mfma_f32_16x16x32_bf16(qal1, kbh1, sa[j], 0, 0, 0);
    }
    __syncthreads();   // s_cp staged; S buffer free
#pragma unroll
    for (int j = 0; j < 8; j++) {
        int kc = w * 128 + j * 16 + lm;
#pragma unroll
        for (int r = 0; r < 4; r++)
            S[(quad * 4 + r) * 516 + kc] = sa[j][r] * 0.125f;
    }
    __syncthreads();

    // ---- phase 2a: softmax + mask + renorm factor (16 lanes per row) ----
    {
        int r = t >> 4, ln = t & 15;
        float m = -1e30f;
        for (int k = ln; k < LL; k += 16) m = fmaxf(m, S[r * 516 + k]);
#pragma unroll
        for (int off = 8; off > 0; off >>= 1) m = fmaxf(m, __shfl_xor(m, off, 16));
        float4 cq = *(float4*)&s_cp[(q0 + r) * 4];
        float Z = 0.f, Sm = 0.f;
        for (int k = ln; k < LL; k += 16) {
            float e = expf(S[r * 516 + k] - m);
            float4 ck = *(float4*)&s_cp[k * 4];
            float mask = cq.x * ck.x + cq.y * ck.y + cq.z * ck.z + cq.w * ck.w;
            float a = e * mask;
            Z += e; Sm += a;
            S[r * 516 + k] = a;
        }
#pragma unroll
        for (int off = 8; off > 0; off >>= 1) {
            Z += __shfl_xor(Z, off, 16);
            Sm += __shfl_xor(Sm, off, 16);
        }
        if (ln == 0) s_inv[r] = 1.f / (Sm + 1e-6f * Z);
    }
    __syncthreads();

    // ---- phase 2b: normalize into regs + plain coalesced write of per-head P ----
    float4 pv[8];
#pragma unroll
    for (int i = 0; i < 8; i++) {
        int e = t + i * 256;                 // float4 unit, 2048 total
        int r2 = e >> 7, k4 = (e & 127) * 4;
        float4 p = *(float4*)&S[r2 * 516 + k4];
        float inv = s_inv[r2];
        p.x *= inv; p.y *= inv; p.z *= inv; p.w *= inv;
        pv[i] = p;
        *(float4*)&attn_h[(((size_t)((b * 8 + hl) * LL + q0 + r2)) * LL) + k4] = p;
    }
    __syncthreads();   // all reads of S done; overwrite with Ph/Pl
#pragma unroll
    for (int i = 0; i < 8; i++) {
        int e = t + i * 256;
        int r2 = e >> 7, k4 = (e & 127) * 4;
        float c[4] = {pv[i].x, pv[i].y, pv[i].z, pv[i].w};
        u16x4 hv, lv;
#pragma unroll
        for (int j = 0; j < 4; j++) {
            unsigned short hb = f2bf(c[j]);
            hv[j] = hb;
            lv[j] = f2bf(c[j] - bf2f(hb));
        }
        *(u16x4*)&Ph[r2 * 520 + k4] = hv;
        *(u16x4*)&Pl[r2 * 520 + k4] = lv;
    }
    __syncthreads();

    // ---- phase 3: ctx = P @ V via Vt ----
    int dn = w * 16 + lm;
    const unsigned short* vrh = vth + ((size_t)bh * DK + dn) * LL;
    const unsigned short* vrl = vtl + ((size_t)bh * DK + dn) * LL;
    floatx4 ca = {};
#pragma unroll
    for (int kc = 0; kc < 16; kc++) {
        int kb = kc * 32 + quad * 8;
        short8 pah = *(const short8*)&Ph[lm * 520 + kb];
        short8 pal = *(const short8*)&Pl[lm * 520 + kb];
        short8 vbh = *(const short8*)(vrh + kb);
        short8 vbl = *(const short8*)(vrl + kb);
        ca = __builtin_amdgcn_mfma_f32_16x16x32_bf16(pah, vbh, ca, 0, 0, 0);
        ca = __builtin_amdgcn_mfma_f32_16x16x32_bf16(pah, vbl, ca, 0, 0, 0);
        ca = __builtin_amdgcn_mfma_f32_16x16x32_bf16(pal, vbh, ca, 0, 0, 0);
    }
#pragma unroll
    for (int r = 0; r < 4; r++)
        ctxf[((size_t)(b * LL + q0 + quad * 4 + r)) * DD + h * DK + dn] = ca[r];
}

// ---------------- reduce per-head probs into attn mean (8 heads per pass) ----------------
__global__ __launch_bounds__(256)
void attn_reduce(const float* __restrict__ attn_h, float* __restrict__ attn_out,
                 int accumulate) {
    int e = blockIdx.x * 256 + threadIdx.x;  // float4 unit; total B*L*L/4
    int b = e >> 16;
    int rem = e & 65535;
    float4 s = {0.f, 0.f, 0.f, 0.f};
#pragma unroll
    for (int hl = 0; hl < 8; hl++) {
        float4 v = ((const float4*)attn_h)[(((size_t)(b * 8 + hl)) << 16) + rem];
        s.x += v.x; s.y += v.y; s.z += v.z; s.w += v.w;
    }
    float4* o = (float4*)attn_out + (((size_t)b) << 16) + rem;
    const float sc = 1.0f / (float)HH;
    float4 prev = {0.f, 0.f, 0.f, 0.f};
    if (accumulate) prev = *o;
    prev.x += s.x * sc; prev.y += s.y * sc; prev.z += s.z * sc; prev.w += s.w * sc;
    *o = prev;
}

// ---------------- MI: pdf + wsum ----------------
__global__ __launch_bounds__(256)
void wsum_kernel(const float* __restrict__ lpdf, const float* __restrict__ cp,
                 const unsigned int* __restrict__ maxenc,
                 float* __restrict__ pdf_out, float* __restrict__ wsum_out) {
    __shared__ float s_red[256];
    int t = threadIdx.x;
    int bh = blockIdx.x;
    float M = fdec(*maxenc);
    float a[CC] = {0.f, 0.f, 0.f, 0.f};
    for (int li = 0; li < 2; li++) {
        int l = t + li * 256;
        size_t idx = ((size_t)bh * LL + l) * CC;
        float p0 = expf(lpdf[idx + 0] - M);
        float p1 = expf(lpdf[idx + 1] - M);
        float p2 = expf(lpdf[idx + 2] - M);
        float p3 = expf(lpdf[idx + 3] - M);
        float pd = p0 + p1 + p2 + p3;
        pdf_out[(size_t)bh * LL + l] = pd;
        a[0] += cp[idx + 0] * pd; a[1] += cp[idx + 1] * pd;
        a[2] += cp[idx + 2] * pd; a[3] += cp[idx + 3] * pd;
    }
#pragma unroll
    for (int c = 0; c < CC; c++) {
        float tot = block_sum256(a[c], s_red);
        if (t == 0) wsum_out[bh * CC + c] = tot;
    }
}

// ---------------- MI: pairwise head overlap ----------------
__global__ __launch_bounds__(256)
void mi_kernel(const float* __restrict__ cp, const float* __restrict__ pdf,
               const float* __restrict__ wsum, float* __restrict__ mi_out) {
    __shared__ float s_q[HH * CC];
    __shared__ float s_c[HH * CC];
    __shared__ float s_red[256];
    int t = threadIdx.x;
    int b = blockIdx.x >> 9;
    int l = blockIdx.x & 511;
    if (t < HH * CC) {
        int i = t >> 2, c = t & 3;
        float cpv = cp[((size_t)(b * HH + i) * LL + l) * CC + c];
        s_c[t] = cpv;
        float w = cpv * pdf[(size_t)(b * HH + i) * LL + l];
        float ws = wsum[(b * HH + i) * CC + c];
        s_q[t] = w / fmaxf(ws, 1e-6f);
    }
    __syncthreads();
    int i = t >> 4, j = t & 15;
    float sdot = 0.f;
#pragma unroll
    for (int c = 0; c < CC; c++) sdot += s_q[i * 4 + c] * s_c[j * 4 + c];
    float mi_p = fminf(sdot, 1.f);
    float val = (i != j) ? logf(1.f - mi_p + 1e-6f) : 0.f;
    float tot = block_sum256(val, s_red);
    if (t == 0) atomicAdd(mi_out + b, -10.f * tot * (1.0f / ((float)LL * HH * HH)));
}

// ---------------- launcher ----------------
extern "C" void kernel_launch(void* const* d_in, const int* in_sizes, int n_in,
                              void* d_out, int out_size, void* d_ws, size_t ws_size,
                              hipStream_t stream) {
    (void)in_sizes; (void)n_in; (void)out_size; (void)ws_size;
    const float* query  = (const float*)d_in[0];
    const float* key    = (const float*)d_in[1];
    const float* value  = (const float*)d_in[2];
    const float* Wq     = (const float*)d_in[3];
    const float* bq     = (const float*)d_in[4];
    const float* Wk     = (const float*)d_in[5];
    const float* bk     = (const float*)d_in[6];
    const float* Wv     = (const float*)d_in[7];
    const float* bv     = (const float*)d_in[8];
    const float* Wo     = (const float*)d_in[9];
    const float* bo     = (const float*)d_in[10];
    const float* Wsem   = (const float*)d_in[11];
    const float* bsem   = (const float*)d_in[12];
    const float* Whead  = (const float*)d_in[13];
    const float* bhead  = (const float*)d_in[14];
    const float* tokmu  = (const float*)d_in[15];
    const float* toklv  = (const float*)d_in[16];
    const float* toklp  = (const float*)d_in[17];
    const float* headmu = (const float*)d_in[18];
    const float* headlv = (const float*)d_in[19];
    const float* headlp = (const float*)d_in[20];

    float* ws   = (float*)d_ws;
    const size_t NBLD = (size_t)BB * LL * DD;      // 4194304
    float* q    = ws;                               // fp32 q (cluster/alv need it)
    float* ctxf = ws + NBLD;
    float* alvq = ws + 2 * NBLD;
    float* alvh = alvq + (size_t)BB * HH * LL;
    float* cpq  = alvh + (size_t)BB * HH * LL;
    float* cph  = cpq + (size_t)BB * HH * LL * CC;
    float* lpdfh= cph + (size_t)BB * HH * LL * CC;
    float* pdfb = lpdfh + (size_t)BB * HH * LL * CC;
    float* wsumb= pdfb + (size_t)BB * HH * LL;
    unsigned int* maxenc = (unsigned int*)(wsumb + (size_t)BB * HH * CC);
    float* attn_h = (float*)(maxenc + 4);           // 8 heads x B x L x L fp32 = 67 MB

    // bf16 scratch (ushort)
    unsigned short* us = (unsigned short*)(attn_h + (size_t)BB * 8 * LL * LL);
    const size_t WSZ = (size_t)DD * DD;            // 1048576
    unsigned short* ist_h = us;                    // input staging (reused serially)
    unsigned short* ist_l = ist_h + NBLD;
    unsigned short* qoh = ist_l + NBLD;
    unsigned short* qol = qoh + NBLD;
    unsigned short* koh = qol + NBLD;
    unsigned short* kol = koh + NBLD;
    unsigned short* voh = kol + NBLD;
    unsigned short* vol = voh + NBLD;
    unsigned short* vth = vol + NBLD;              // Vt[d][l] per (b,h)
    unsigned short* vtl = vth + NBLD;
    unsigned short* wqh = vtl + NBLD;
    unsigned short* wql = wqh + WSZ;
    unsigned short* wkh = wql + WSZ;
    unsigned short* wkl = wkh + WSZ;
    unsigned short* wvh = wkl + WSZ;
    unsigned short* wvl = wvh + WSZ;
    unsigned short* woh = wvl + WSZ;
    unsigned short* wol = woh + WSZ;

    float* out      = (float*)d_out;
    float* attn_out = out + NBLD;
    float* kl_out   = attn_out + (size_t)BB * LL * LL;
    float* div_out  = kl_out + BB;
    float* mi_out   = div_out + BB;

    hipMemsetAsync(kl_out, 0, 3 * BB * sizeof(float), stream);
    hipMemsetAsync(maxenc, 0, sizeof(unsigned int), stream);

    dim3 wg(16, 16);
    wconv_kernel<<<wg, 256, 0, stream>>>(Wq, wqh, wql);
    wconv_kernel<<<wg, 256, 0, stream>>>(Wk, wkh, wkl);
    wconv_kernel<<<wg, 256, 0, stream>>>(Wv, wvh, wvl);
    wconv_kernel<<<wg, 256, 0, stream>>>(Wo, woh, wol);

    dim3 gg(DD / 128, BB * LL / 128);  // (8, 32)
    convert_hilo<<<NBLD / 1024, 256, 0, stream>>>(query, ist_h, ist_l);
    mfma_gemm_bias<<<gg, 256, 0, stream>>>(ist_h, ist_l, wqh, wql, bq, q, qoh, qol);
    convert_hilo<<<NBLD / 1024, 256, 0, stream>>>(key, ist_h, ist_l);
    mfma_gemm_bias<<<gg, 256, 0, stream>>>(ist_h, ist_l, wkh, wkl, bk, nullptr, koh, kol);
    convert_hilo<<<NBLD / 1024, 256, 0, stream>>>(value, ist_h, ist_l);
    mfma_gemm_bias<<<gg, 256, 0, stream>>>(ist_h, ist_l, wvh, wvl, bv, nullptr, voh, vol);

    dim3 vtg(LL / 128, HH, BB);
    vt_prep<<<vtg, 256, 0, stream>>>(voh, vth);
    vt_prep<<<vtg, 256, 0, stream>>>(vol, vtl);

    alv_gemm<<<BB * LL / 16, 256, 0, stream>>>(q, Wsem, bsem, alvq);
    cluster_kernel<<<BB * HH * 2, 256, 0, stream>>>(q, alvq, tokmu, toklv, toklp,
                                                    cpq, nullptr, nullptr, kl_out, 0);
    pairstats_kernel<<<BB * HH * 8, 256, 0, stream>>>(cpq, div_out, nullptr, 0);

    for (int h0 = 0; h0 < HH; h0 += 8) {
        attn3_kernel<<<dim3(LL / 16, 8, BB), 256, 0, stream>>>(
            qoh, qol, koh, kol, vth, vtl, cpq, ctxf, attn_h, h0);
        attn_reduce<<<BB * LL * LL / 4 / 256, 256, 0, stream>>>(
            attn_h, attn_out, h0 > 0 ? 1 : 0);
    }

    convert_hilo<<<NBLD / 1024, 256, 0, stream>>>(ctxf, ist_h, ist_l);
    alv_gemm<<<BB * LL / 16, 256, 0, stream>>>(ctxf, Whead, bhead, alvh);
    cluster_kernel<<<BB * HH * 2, 256, 0, stream>>>(ctxf, alvh, headmu, headlv, headlp,
                                                    cph, lpdfh, maxenc, kl_out, 1);
    pairstats_kernel<<<BB * HH * 8, 256, 0, stream>>>(cph, div_out, mi_out, 1);
    wsum_kernel<<<BB * HH, 256, 0, stream>>>(lpdfh, cph, maxenc, pdfb, wsumb);
    mi_kernel<<<BB * LL, 256, 0, stream>>>(cph, pdfb, wsumb, mi_out);
    mfma_gemm_bias<<<gg, 256, 0, stream>>>(ist_h, ist_l, woh, wol, bo, out, nullptr, nullptr);
}